// Round 9
// baseline (207.526 us; speedup 1.0000x reference)
//
#include <hip/hip_runtime.h>
#include <hip/hip_bf16.h>

#define NND 2048
#define BBATCH 4
#define SS 1024
#define SFZ 384
#define IFZ 256
#define HH 8
#define AA 64
#define HA 512
#define GRP 12          // nodes per mega-block (64 groups x 12 = 768 capacity)
#define NGPB 64         // groups per batch
#define MEGA_BLKS (BBATCH * NGPB)   // 256
#define LOG_BLKS (BBATCH * 12)      // 48 logits blocks (64-node xblks)

typedef __attribute__((ext_vector_type(8))) short bf16x8;
typedef __attribute__((ext_vector_type(4))) float f32x4;

__device__ __forceinline__ unsigned short f2bf(float f) {
    union { float f; unsigned u; } a; a.f = f;
    unsigned r = a.u + 0x7fffu + ((a.u >> 16) & 1u);
    return (unsigned short)(r >> 16);
}
__device__ __forceinline__ float bf2f(unsigned short u) {
    return __uint_as_float((unsigned)u << 16);
}

__device__ __forceinline__ bf16x8 cvt8(const float* __restrict__ p) {
    const float4 f0 = *(const float4*)p;
    const float4 f1 = *(const float4*)(p + 4);
    bf16x8 o;
    o[0] = (short)f2bf(f0.x); o[1] = (short)f2bf(f0.y);
    o[2] = (short)f2bf(f0.z); o[3] = (short)f2bf(f0.w);
    o[4] = (short)f2bf(f1.x); o[5] = (short)f2bf(f1.y);
    o[6] = (short)f2bf(f1.z); o[7] = (short)f2bf(f1.w);
    return o;
}

// --- forced-issue async loads (asm volatile preserves issue order) ---
__device__ __forceinline__ bf16x8 gld16(const unsigned short* p) {
    bf16x8 r;
    asm volatile("global_load_dwordx4 %0, %1, off" : "=&v"(r) : "v"(p));
    return r;
}
__device__ __forceinline__ f32x4 gldf4(const float* p) {
    f32x4 r;
    asm volatile("global_load_dwordx4 %0, %1, off" : "=&v"(r) : "v"(p));
    return r;
}
#define VMWAIT0() do { \
    asm volatile("s_waitcnt vmcnt(0)" ::: "memory"); \
    __builtin_amdgcn_sched_barrier(0); \
} while (0)

// ---------------------------------------------------------------------------
// Kernel P: prep (unchanged from R8).
// ---------------------------------------------------------------------------
__device__ __forceinline__ void tile_transpose(
    const float* __restrict__ src, unsigned short* __restrict__ dst,
    int K, int N, int kt, int nt, int t)
{
    __shared__ unsigned short tile[64][65];
    const int k0 = kt * 64, n0 = nt * 64;
    const int tr = t >> 6, tc = t & 63;
    #pragma unroll
    for (int r = 0; r < 16; ++r)
        tile[tr + r*4][tc] = f2bf(src[(size_t)(k0 + tr + r*4) * N + n0 + tc]);
    __syncthreads();
    #pragma unroll
    for (int r = 0; r < 16; ++r)
        dst[(size_t)(n0 + tr + r*4) * K + k0 + tc] = tile[tc][tr + r*4];
}

__global__ __launch_bounds__(256) void prep_kernel(
    const float* __restrict__ Wk, const float* __restrict__ Wv,
    const float* __restrict__ Wq, const float* __restrict__ Wg,
    const float* __restrict__ Wback,
    const void* __restrict__ mask_raw, const void* __restrict__ batch_raw,
    unsigned short* __restrict__ WkT, unsigned short* __restrict__ WvT,
    unsigned short* __restrict__ WqT, unsigned short* __restrict__ WgT,
    unsigned short* __restrict__ WbackT,
    float* __restrict__ mask_f, int* __restrict__ seg)
{
    const int bx = blockIdx.x, t = threadIdx.x;
    if (bx < 48)  { tile_transpose(Wk, WkT, SFZ, HA, bx/8, bx%8, t); return; }
    if (bx < 96)  { const int i = bx-48;  tile_transpose(Wv, WvT, SFZ, HA, i/8, i%8, t); return; }
    if (bx < 128) { const int i = bx-96;  tile_transpose(Wq, WqT, IFZ, HA, i/8, i%8, t); return; }
    if (bx < 160) { const int i = bx-128; tile_transpose(Wg, WgT, IFZ, HA, i/8, i%8, t); return; }
    if (bx < 192) { const int i = bx-160; tile_transpose(Wback, WbackT, HA, IFZ, i/4, i%4, t); return; }
    __shared__ int fl[4];
    __shared__ int fb;
    __shared__ int cnt[4];
    if (t < 4) { fl[t] = 0; cnt[t] = 0; }
    if (t == 0) fb = 0;
    __syncthreads();
    const unsigned char*  mb = (const unsigned char*)mask_raw;
    const unsigned short* mh = (const unsigned short*)mask_raw;
    const unsigned int*   mw = (const unsigned int*)mask_raw;
    int f0 = 0, f1 = 0, f2 = 0, f3 = 0;
    for (int i = t; i < 2048; i += 256) {
        unsigned short h = mh[i];
        if (h == 0x3f80u) f0 = 1;
        if ((i & 1) == 0 && h != 0) f1 = 1;
    }
    for (int i = t; i < 4096; i += 256)
        if ((i & 3) != 0 && mb[i] != 0) f2 = 1;
    for (int i = t; i < 1024; i += 256)
        if ((i & 1) != 0 && mw[i] != 0) f3 = 1;
    const int* bw = (const int*)batch_raw;
    int f4 = 0;
    for (int i = t + 1; i < 2048; i += 256)
        if (bw[i] < bw[i-1]) f4 = 1;
    if (f0) atomicOr(&fl[0], 1);
    if (f1) atomicOr(&fl[1], 1);
    if (f2) atomicOr(&fl[2], 1);
    if (f3) atomicOr(&fl[3], 1);
    if (f4) atomicOr(&fb, 1);
    __syncthreads();
    int mode;
    if (fl[0])      mode = fl[1] ? 1 : 0;
    else if (fl[2]) mode = 2;
    else if (fl[3]) mode = 3;
    else            mode = 4;
    for (int s = t; s < BBATCH*SS; s += 256) {
        int m;
        switch (mode) {
            case 0:  m = (mw[s]   != 0); break;
            case 1:  m = (mh[s]   != 0); break;
            case 2:  m = (mb[s]   != 0); break;
            case 3:  m = (mw[s]   != 0); break;
            default: m = (mw[2*s] != 0); break;
        }
        mask_f[s] = m ? 1.0f : 0.0f;
    }
    const int b64 = fb;
    for (int i = t; i < NND; i += 256) {
        const int bv = (b64 ? bw[2*i] : bw[i]) & 3;
        atomicAdd(&cnt[bv], 1);
    }
    __syncthreads();
    if (t == 0) {
        int s = 0;
        for (int b = 0; b < 4; ++b) { seg[2*b] = s; s += cnt[b]; seg[2*b+1] = s; }
    }
}

// ---------------------------------------------------------------------------
// Kernel 1: fused MFMA projections (unchanged from R8).
// ---------------------------------------------------------------------------
__global__ __launch_bounds__(256, 2) void proj_mfma(
    const float* __restrict__ emb, const float* __restrict__ x,
    const unsigned short* __restrict__ WkT, const unsigned short* __restrict__ WvT,
    const unsigned short* __restrict__ WqT, const unsigned short* __restrict__ WgT,
    const float* __restrict__ bg,
    unsigned short* __restrict__ k_blk, unsigned short* __restrict__ vT_bf,
    unsigned short* __restrict__ q_bf, float* __restrict__ gate_ws)
{
    __shared__ unsigned short v_l[16][520];   // 16.6 KB
    const int t = threadIdx.x, w = t >> 6, lane = t & 63;
    const int m16 = lane & 15, quad = lane >> 4;
    const int bx = blockIdx.x;
    if (bx < 256) {
        const int r0 = bx * 16;
        const int b = r0 >> 10, srow = r0 & (SS - 1);
        const float* ap = emb + (size_t)(r0 + m16) * SFZ + quad * 8;
        bf16x8 af[12];
        #pragma unroll
        for (int j = 0; j < 12; ++j) af[j] = cvt8(ap + j * 32);
        #pragma unroll
        for (int tensor = 0; tensor < 2; ++tensor) {
            const unsigned short* Wt = tensor ? WvT : WkT;
            #pragma unroll
            for (int g = 0; g < 2; ++g) {
                const int n0g = w * 128 + g * 64;
                const unsigned short* bp0 = Wt + (size_t)(n0g +  0 + m16) * SFZ + quad * 8;
                const unsigned short* bp1 = Wt + (size_t)(n0g + 16 + m16) * SFZ + quad * 8;
                const unsigned short* bp2 = Wt + (size_t)(n0g + 32 + m16) * SFZ + quad * 8;
                const unsigned short* bp3 = Wt + (size_t)(n0g + 48 + m16) * SFZ + quad * 8;
                f32x4 a0 = (f32x4){0.f, 0.f, 0.f, 0.f};
                f32x4 a1 = a0, a2 = a0, a3 = a0;
                bf16x8 wb[24];
                #pragma unroll
                for (int j = 0; j < 6; ++j) {
                    wb[j*4+0] = gld16(bp0 + j * 32);
                    wb[j*4+1] = gld16(bp1 + j * 32);
                    wb[j*4+2] = gld16(bp2 + j * 32);
                    wb[j*4+3] = gld16(bp3 + j * 32);
                }
                VMWAIT0();
                #pragma unroll
                for (int j = 0; j < 6; ++j) {
                    a0 = __builtin_amdgcn_mfma_f32_16x16x32_bf16(af[j], wb[j*4+0], a0, 0, 0, 0);
                    a1 = __builtin_amdgcn_mfma_f32_16x16x32_bf16(af[j], wb[j*4+1], a1, 0, 0, 0);
                    a2 = __builtin_amdgcn_mfma_f32_16x16x32_bf16(af[j], wb[j*4+2], a2, 0, 0, 0);
                    a3 = __builtin_amdgcn_mfma_f32_16x16x32_bf16(af[j], wb[j*4+3], a3, 0, 0, 0);
                }
                #pragma unroll
                for (int j = 6; j < 12; ++j) {
                    wb[(j-6)*4+0] = gld16(bp0 + j * 32);
                    wb[(j-6)*4+1] = gld16(bp1 + j * 32);
                    wb[(j-6)*4+2] = gld16(bp2 + j * 32);
                    wb[(j-6)*4+3] = gld16(bp3 + j * 32);
                }
                VMWAIT0();
                #pragma unroll
                for (int j = 6; j < 12; ++j) {
                    a0 = __builtin_amdgcn_mfma_f32_16x16x32_bf16(af[j], wb[(j-6)*4+0], a0, 0, 0, 0);
                    a1 = __builtin_amdgcn_mfma_f32_16x16x32_bf16(af[j], wb[(j-6)*4+1], a1, 0, 0, 0);
                    a2 = __builtin_amdgcn_mfma_f32_16x16x32_bf16(af[j], wb[(j-6)*4+2], a2, 0, 0, 0);
                    a3 = __builtin_amdgcn_mfma_f32_16x16x32_bf16(af[j], wb[(j-6)*4+3], a3, 0, 0, 0);
                }
                f32x4 dd[4] = {a0, a1, a2, a3};
                if (tensor == 0) {
                    #pragma unroll
                    for (int u = 0; u < 4; ++u) {
                        const int n0 = n0g + u * 16;
                        const int head = n0 >> 6, coff = (n0 & 63) + m16;
                        unsigned short* kb = k_blk + (((size_t)(b * HH + head)) * SS) * 64 + coff;
                        #pragma unroll
                        for (int r = 0; r < 4; ++r)
                            kb[(size_t)(srow + quad * 4 + r) * 64] = f2bf(dd[u][r]);
                    }
                } else {
                    #pragma unroll
                    for (int u = 0; u < 4; ++u) {
                        const int c0 = n0g + u * 16 + m16;
                        #pragma unroll
                        for (int r = 0; r < 4; ++r)
                            v_l[quad * 4 + r][c0] = f2bf(dd[u][r]);
                    }
                }
            }
        }
        __syncthreads();
        for (int c = t; c < HA; c += 256) {
            unsigned short tmp[16];
            #pragma unroll
            for (int s = 0; s < 16; ++s) tmp[s] = v_l[s][c];
            unsigned short* dst = vT_bf + ((size_t)b * HA + c) * SS + srow;
            *(uint4*)dst       = ((const uint4*)tmp)[0];
            *(uint4*)(dst + 8) = ((const uint4*)tmp)[1];
        }
    } else {
        const int i = bx - 256;
        const int r0 = (i >> 1) * 16;
        const int half = i & 1;
        const float* ap = x + (size_t)(r0 + m16) * IFZ + quad * 8;
        bf16x8 af[8];
        #pragma unroll
        for (int j = 0; j < 8; ++j) af[j] = cvt8(ap + j * 32);
        const int n0b = half * 256 + w * 64;
        #pragma unroll
        for (int tensor = 0; tensor < 2; ++tensor) {
            const unsigned short* Wt = tensor ? WgT : WqT;
            const unsigned short* bp0 = Wt + (size_t)(n0b +  0 + m16) * IFZ + quad * 8;
            const unsigned short* bp1 = Wt + (size_t)(n0b + 16 + m16) * IFZ + quad * 8;
            const unsigned short* bp2 = Wt + (size_t)(n0b + 32 + m16) * IFZ + quad * 8;
            const unsigned short* bp3 = Wt + (size_t)(n0b + 48 + m16) * IFZ + quad * 8;
            bf16x8 wb[32];
            #pragma unroll
            for (int j = 0; j < 8; ++j) {
                wb[j*4+0] = gld16(bp0 + j * 32);
                wb[j*4+1] = gld16(bp1 + j * 32);
                wb[j*4+2] = gld16(bp2 + j * 32);
                wb[j*4+3] = gld16(bp3 + j * 32);
            }
            VMWAIT0();
            f32x4 a0 = (f32x4){0.f, 0.f, 0.f, 0.f};
            f32x4 a1 = a0, a2 = a0, a3 = a0;
            #pragma unroll
            for (int j = 0; j < 8; ++j) {
                a0 = __builtin_amdgcn_mfma_f32_16x16x32_bf16(af[j], wb[j*4+0], a0, 0, 0, 0);
                a1 = __builtin_amdgcn_mfma_f32_16x16x32_bf16(af[j], wb[j*4+1], a1, 0, 0, 0);
                a2 = __builtin_amdgcn_mfma_f32_16x16x32_bf16(af[j], wb[j*4+2], a2, 0, 0, 0);
                a3 = __builtin_amdgcn_mfma_f32_16x16x32_bf16(af[j], wb[j*4+3], a3, 0, 0, 0);
            }
            f32x4 dd[4] = {a0, a1, a2, a3};
            if (tensor == 0) {
                #pragma unroll
                for (int u = 0; u < 4; ++u) {
                    const int n0 = n0b + u * 16;
                    #pragma unroll
                    for (int r = 0; r < 4; ++r)
                        q_bf[(size_t)(r0 + quad * 4 + r) * HA + n0 + m16] = f2bf(dd[u][r]);
                }
            } else {
                #pragma unroll
                for (int u = 0; u < 4; ++u) {
                    const int n0 = n0b + u * 16;
                    const float bgv = bg[n0 + m16];
                    #pragma unroll
                    for (int r = 0; r < 4; ++r)
                        gate_ws[(size_t)(r0 + quad * 4 + r) * HA + n0 + m16] =
                            1.f / (1.f + __expf(-(dd[u][r] + bgv)));
                }
            }
        }
    }
}

// ---------------------------------------------------------------------------
// Kernel 2: FULLY FUSED attention + gate + Wback + residual + LN.
// Blocks [0,256): mega blocks. 512 thr (8 waves), wave w = head w.
// Block owns 12 nodes x ALL heads x full S=1024 (8 chunks, online softmax).
// No splits -> no part_O/part_ml, back-end fused in-block (3 barriers).
// Blocks [256,304): logits role (decoupled raw-score recompute).
// Fragment mappings copied verbatim from R7/R8-verified kernels.
// ---------------------------------------------------------------------------
__global__ __launch_bounds__(512, 2) void attn_back_fused(
    const unsigned short* __restrict__ k_blk, const unsigned short* __restrict__ vT_bf,
    const unsigned short* __restrict__ q_bf, const float* __restrict__ mask_f,
    const int* __restrict__ seg, const float* __restrict__ gate_ws,
    const unsigned short* __restrict__ WbackT, const float* __restrict__ x,
    const float* __restrict__ bback, const float* __restrict__ gamma,
    const float* __restrict__ beta, float* __restrict__ out,
    float* __restrict__ out_logits)
{
    __shared__ __align__(16) char smem[34816];
    const int bid = blockIdx.x, t = threadIdx.x;
    const int w = t >> 6, lane = t & 63;
    const int m16 = lane & 15, quad = lane >> 4;

    if (bid >= MEGA_BLKS) {
        // ================== logits role (8 waves x 128-s chunks) ==========
        const int lid = bid - MEGA_BLKS;          // [0,48)
        const int b = lid / 12, xblk = lid % 12;
        const int s0 = w * 128;
        const int nbase = seg[2*b] + xblk * 64;
        const int nend  = seg[2*b + 1];
        if (nbase >= nend) return;
        const unsigned short* kb0 = k_blk + ((size_t)(b * HH + 0)) * SS * 64;
        const unsigned short* kb1 = k_blk + ((size_t)(b * HH + 1)) * SS * 64;
        bf16x8 k0[16], k1[16];
        #pragma unroll
        for (int st = 0; st < 8; ++st) {
            const unsigned short* kp0 = kb0 + (size_t)(s0 + st * 16 + m16) * 64 + quad * 8;
            const unsigned short* kp1 = kb1 + (size_t)(s0 + st * 16 + m16) * 64 + quad * 8;
            k0[2*st]   = gld16(kp0);
            k0[2*st+1] = gld16(kp0 + 32);
            k1[2*st]   = gld16(kp1);
            k1[2*st+1] = gld16(kp1 + 32);
        }
        VMWAIT0();
        for (int g = 0; g < 4; ++g) {
            const int n0g = nbase + g * 16;
            if (n0g >= nend) break;
            const int nvalid = min(16, nend - n0g);
            int nq = n0g + m16; if (nq >= nend) nq = nend - 1;
            const unsigned short* qp = q_bf + (size_t)nq * HA + quad * 8;
            const bf16x8 q0a = gld16(qp);
            const bf16x8 q0b = gld16(qp + 32);
            const bf16x8 q1a = gld16(qp + 64);
            const bf16x8 q1b = gld16(qp + 96);
            VMWAIT0();
            #pragma unroll
            for (int st = 0; st < 8; ++st) {
                f32x4 acc = (f32x4){0.f, 0.f, 0.f, 0.f};
                acc = __builtin_amdgcn_mfma_f32_16x16x32_bf16(q0a, k0[2*st],   acc, 0, 0, 0);
                acc = __builtin_amdgcn_mfma_f32_16x16x32_bf16(q0b, k0[2*st+1], acc, 0, 0, 0);
                acc = __builtin_amdgcn_mfma_f32_16x16x32_bf16(q1a, k1[2*st],   acc, 0, 0, 0);
                acc = __builtin_amdgcn_mfma_f32_16x16x32_bf16(q1b, k1[2*st+1], acc, 0, 0, 0);
                #pragma unroll
                for (int r = 0; r < 4; ++r) {
                    const int row = quad * 4 + r;
                    if (row < nvalid)
                        out_logits[(size_t)(n0g + row) * SS + s0 + st * 16 + m16] =
                            acc[r] * 0.125f;
                }
            }
        }
        return;
    }

    // ================== mega role ==================
    const int xcd = bid & 7;
    const int b   = xcd >> 1;
    const int g   = (bid >> 3) * 2 + (xcd & 1);   // [0,64)
    const int nbase = seg[2*b] + g * GRP;
    const int nend  = seg[2*b + 1];
    if (nbase >= nend) return;                     // block-uniform
    const int nvalid = min(GRP, nend - nbase);
    const int h = w;

    unsigned short (*Pw)[136] = (unsigned short (*)[136])(smem + w * 4352);

    const unsigned short* kb = k_blk + ((size_t)(b * HH + h)) * SS * 64;
    const unsigned short* vb = vT_bf + ((size_t)b * HA + h * AA) * SS;

    // ---- q once (block's nodes fixed) ----
    int nq0 = nbase + m16; if (nq0 >= nend) nq0 = nend - 1;
    const unsigned short* qp = q_bf + (size_t)nq0 * HA + h * AA + quad * 8;
    const bf16x8 qc0 = gld16(qp);
    const bf16x8 qc1 = gld16(qp + 32);
    // ---- chunk 0: K + mask ----
    bf16x8 kf[16];
    #pragma unroll
    for (int st = 0; st < 8; ++st) {
        const unsigned short* kp = kb + (size_t)(st * 16 + m16) * 64 + quad * 8;
        kf[2*st]   = gld16(kp);
        kf[2*st+1] = gld16(kp + 32);
    }
    f32x4 mkv[8];
    #pragma unroll
    for (int st = 0; st < 8; ++st)
        mkv[st] = gldf4(mask_f + b * SS + st * 16 + quad * 4);
    VMWAIT0();
    unsigned bm = 0u;
    #pragma unroll
    for (int st = 0; st < 8; ++st)
        #pragma unroll
        for (int r = 0; r < 4; ++r)
            if (mkv[st][r] > 0.5f) bm |= (1u << (st * 4 + r));

    float M = -1.0e30f, l = 0.f;
    f32x4 facc[4];
    #pragma unroll
    for (int a = 0; a < 4; ++a) facc[a] = (f32x4){0.f, 0.f, 0.f, 0.f};

    for (int c = 0; c < 8; ++c) {
        const int s0c = c << 7;
        // ---- QK^T swapped (verified): C[row=s][col=node(m16)] ----
        f32x4 d[8];
        #pragma unroll
        for (int st = 0; st < 8; ++st) {
            f32x4 acc = (f32x4){0.f, 0.f, 0.f, 0.f};
            acc = __builtin_amdgcn_mfma_f32_16x16x32_bf16(kf[2*st],   qc0, acc, 0, 0, 0);
            acc = __builtin_amdgcn_mfma_f32_16x16x32_bf16(kf[2*st+1], qc1, acc, 0, 0, 0);
            #pragma unroll
            for (int r = 0; r < 4; ++r) acc[r] *= 0.125f;
            d[st] = acc;
        }
        // ---- issue V_c; prefetch K_{c+1}, mask_{c+1} (SM hides latency) ----
        bf16x8 vf[16];
        #pragma unroll
        for (int sub = 0; sub < 4; ++sub) {
            const unsigned short* vp0 = vb + (size_t)m16 * SS + s0c + sub * 32 + quad * 8;
            #pragma unroll
            for (int a = 0; a < 4; ++a)
                vf[sub*4+a] = gld16(vp0 + (size_t)(a * 16) * SS);
        }
        if (c < 7) {
            const int s1c = s0c + 128;
            #pragma unroll
            for (int st = 0; st < 8; ++st) {
                const unsigned short* kp = kb + (size_t)(s1c + st * 16 + m16) * 64 + quad * 8;
                kf[2*st]   = gld16(kp);
                kf[2*st+1] = gld16(kp + 32);
            }
            #pragma unroll
            for (int st = 0; st < 8; ++st)
                mkv[st] = gldf4(mask_f + b * SS + s1c + st * 16 + quad * 4);
        }
        __builtin_amdgcn_sched_barrier(0);

        // ---- online softmax (node = m16 per lane) ----
        #pragma unroll
        for (int st = 0; st < 8; ++st)
            #pragma unroll
            for (int r = 0; r < 4; ++r)
                if (!((bm >> (st * 4 + r)) & 1u)) d[st][r] = -3.0e38f;
        float pmax = -3.0e38f;
        #pragma unroll
        for (int st = 0; st < 8; ++st) {
            float a = fmaxf(fmaxf(d[st][0], d[st][1]), fmaxf(d[st][2], d[st][3]));
            pmax = fmaxf(pmax, a);
        }
        pmax = fmaxf(pmax, __shfl_xor(pmax, 16));
        pmax = fmaxf(pmax, __shfl_xor(pmax, 32));
        const float Mn = fmaxf(fmaxf(M, pmax), -1.0e30f);
        const float alpha = __expf(M - Mn);
        float cs = 0.f;
        #pragma unroll
        for (int st = 0; st < 8; ++st)
            #pragma unroll
            for (int r = 0; r < 4; ++r) {
                const float e = __expf(d[st][r] - Mn);
                d[st][r] = e;
                cs += e;
            }
        cs += __shfl_xor(cs, 16);
        cs += __shfl_xor(cs, 32);
        l = l * alpha + cs;
        M = Mn;
        // ---- P -> LDS (verified layout) ----
        #pragma unroll
        for (int st = 0; st < 8; ++st) {
            ushort4 pk;
            pk.x = f2bf(d[st][0]); pk.y = f2bf(d[st][1]);
            pk.z = f2bf(d[st][2]); pk.w = f2bf(d[st][3]);
            *(ushort4*)&Pw[m16][st * 16 + quad * 4] = pk;
        }
        bf16x8 pa[4];
        #pragma unroll
        for (int sub = 0; sub < 4; ++sub)
            pa[sub] = *(const bf16x8*)&Pw[m16][sub * 32 + quad * 8];
        // ---- rescale O accumulator rows (row = node quad*4+r) ----
        float fr0 = __shfl(alpha, quad * 4 + 0);
        float fr1 = __shfl(alpha, quad * 4 + 1);
        float fr2 = __shfl(alpha, quad * 4 + 2);
        float fr3 = __shfl(alpha, quad * 4 + 3);
        #pragma unroll
        for (int a = 0; a < 4; ++a) {
            facc[a][0] *= fr0; facc[a][1] *= fr1;
            facc[a][2] *= fr2; facc[a][3] *= fr3;
        }
        // ---- wait V (+ prefetches); PV accumulate ----
        VMWAIT0();
        #pragma unroll
        for (int sub = 0; sub < 4; ++sub) {
            #pragma unroll
            for (int a = 0; a < 4; ++a)
                facc[a] = __builtin_amdgcn_mfma_f32_16x16x32_bf16(pa[sub], vf[sub*4+a], facc[a], 0, 0, 0);
        }
        if (c < 7) {
            bm = 0u;
            #pragma unroll
            for (int st = 0; st < 8; ++st)
                #pragma unroll
                for (int r = 0; r < 4; ++r)
                    if (mkv[st][r] > 0.5f) bm |= (1u << (st * 4 + r));
        }
    }
    // ---- finalize: 1/l, gate, stage gated O ----
    const float invl = 1.f / (l + 1e-9f);
    const float fl0 = __shfl(invl, quad * 4 + 0);
    const float fl1 = __shfl(invl, quad * 4 + 1);
    const float fl2 = __shfl(invl, quad * 4 + 2);
    const float fl3 = __shfl(invl, quad * 4 + 3);
    float og[4][4];
    #pragma unroll
    for (int a = 0; a < 4; ++a) {
        #pragma unroll
        for (int r = 0; r < 4; ++r) {
            int nn = nbase + quad * 4 + r; if (nn >= nend) nn = nend - 1;
            const float gv = gate_ws[(size_t)nn * HA + h * AA + a * 16 + m16];
            const float fl_ = (r == 0) ? fl0 : (r == 1) ? fl1 : (r == 2) ? fl2 : fl3;
            og[a][r] = facc[a][r] * fl_ * gv;
        }
    }
    __syncthreads();   // all waves done with Pw before gf overwrites it
    unsigned short (*gf_l)[520] = (unsigned short (*)[520])smem;          // 16.6 KB
    float (*nl)[260] = (float (*)[260])(smem + 16640);                    // 16.6 KB
    #pragma unroll
    for (int a = 0; a < 4; ++a)
        #pragma unroll
        for (int r = 0; r < 4; ++r)
            gf_l[quad * 4 + r][h * AA + a * 16 + m16] = f2bf(og[a][r]);
    __syncthreads();   // gf complete
    // ---- Wback GEMM: wave w computes out cols [w*32, w*32+32) ----
    bf16x8 af[16];
    #pragma unroll
    for (int j = 0; j < 16; ++j)
        af[j] = *(const bf16x8*)&gf_l[m16][quad * 8 + j * 32];
    const int n0w = w * 32;
    const unsigned short* bq0 = WbackT + (size_t)(n0w +  0 + m16) * HA + quad * 8;
    const unsigned short* bq1 = WbackT + (size_t)(n0w + 16 + m16) * HA + quad * 8;
    bf16x8 wb[32];
    #pragma unroll
    for (int j = 0; j < 16; ++j) {
        wb[2*j]   = gld16(bq0 + j * 32);
        wb[2*j+1] = gld16(bq1 + j * 32);
    }
    VMWAIT0();
    f32x4 a0 = (f32x4){0.f, 0.f, 0.f, 0.f};
    f32x4 a1 = a0;
    #pragma unroll
    for (int j = 0; j < 16; ++j) {
        a0 = __builtin_amdgcn_mfma_f32_16x16x32_bf16(af[j], wb[2*j],   a0, 0, 0, 0);
        a1 = __builtin_amdgcn_mfma_f32_16x16x32_bf16(af[j], wb[2*j+1], a1, 0, 0, 0);
    }
    {
        f32x4 dd[2] = {a0, a1};
        #pragma unroll
        for (int u = 0; u < 2; ++u) {
            const int n0 = n0w + u * 16;
            const float bb = bback[n0 + m16];
            #pragma unroll
            for (int r = 0; r < 4; ++r)
                nl[quad * 4 + r][n0 + m16] = dd[u][r] + bb;
        }
    }
    __syncthreads();   // nl complete
    // ---- residual + LN: 512 thr -> 16 row-slots x 32 lanes ----
    const int row = t >> 5, li = t & 31;
    if (row < nvalid) {
        const float* xr = x + (size_t)(nbase + row) * IFZ;
        float yv[8];
        float s1 = 0.f, s2 = 0.f;
        #pragma unroll
        for (int j = 0; j < 8; ++j) {
            const int cc = li + j * 32;
            const float v = fmaf(1.41421356237309515f, xr[cc], nl[row][cc]);
            yv[j] = v; s1 += v; s2 += v * v;
        }
        #pragma unroll
        for (int off = 16; off >= 1; off >>= 1) {
            s1 += __shfl_xor(s1, off);
            s2 += __shfl_xor(s2, off);
        }
        const float mu  = s1 * (1.f / IFZ);
        const float var = s2 * (1.f / IFZ) - mu * mu;
        const float rv  = rsqrtf(var + 1e-5f);
        float* orow = out + (size_t)(nbase + row) * IFZ;
        #pragma unroll
        for (int j = 0; j < 8; ++j) {
            const int cc = li + j * 32;
            orow[cc] = (yv[j] - mu) * rv * gamma[cc] + beta[cc];
        }
    }
}

extern "C" void kernel_launch(void* const* d_in, const int* in_sizes, int n_in,
                              void* d_out, int out_size, void* d_ws, size_t ws_size,
                              hipStream_t stream) {
    const float* x     = (const float*)d_in[0];
    const float* emb   = (const float*)d_in[1];
    const void*  mraw  = d_in[2];
    const void*  braw  = d_in[3];
    const float* Wq    = (const float*)d_in[4];
    const float* Wk    = (const float*)d_in[5];
    const float* Wv    = (const float*)d_in[6];
    const float* Wg    = (const float*)d_in[7];
    const float* bg    = (const float*)d_in[8];
    const float* Wback = (const float*)d_in[9];
    const float* bback = (const float*)d_in[10];
    const float* gamma = (const float*)d_in[11];
    const float* beta  = (const float*)d_in[12];

    char* ws = (char*)d_ws;
    const size_t MB = 1048576;
    size_t off = 0;
    float*          mask_f  = (float*)(ws + off);  off += 16384;
    int*            seg     = (int*)(ws + off);    off += 16384;
    unsigned short* WkT     = (unsigned short*)(ws + off); off += 393216;
    unsigned short* WvT     = (unsigned short*)(ws + off); off += 393216;
    unsigned short* WqT     = (unsigned short*)(ws + off); off += 262144;
    unsigned short* WgT     = (unsigned short*)(ws + off); off += 262144;
    unsigned short* WbackT  = (unsigned short*)(ws + off); off += 262144;
    unsigned short* k_blk   = (unsigned short*)(ws + off); off += 4*MB;
    unsigned short* vT_bf   = (unsigned short*)(ws + off); off += 4*MB;
    unsigned short* q_bf    = (unsigned short*)(ws + off); off += 2*MB;
    float*          gate_ws = (float*)(ws + off); off += 4*MB;

    float* out        = (float*)d_out;
    float* out_logits = out + (size_t)NND * IFZ;

    hipLaunchKernelGGL(prep_kernel, dim3(193), dim3(256), 0, stream,
                       Wk, Wv, Wq, Wg, Wback, mraw, braw,
                       WkT, WvT, WqT, WgT, WbackT, mask_f, seg);
    hipLaunchKernelGGL(proj_mfma, dim3(512), dim3(256), 0, stream,
                       emb, x, WkT, WvT, WqT, WgT, bg, k_blk, vT_bf, q_bf, gate_ws);
    hipLaunchKernelGGL(attn_back_fused, dim3(MEGA_BLKS + LOG_BLKS), dim3(512), 0, stream,
                       k_blk, vT_bf, q_bf, mask_f, seg, gate_ws, WbackT, x,
                       bback, gamma, beta, out, out_logits);
}

// Round 10
// 189.660 us; speedup vs baseline: 1.0942x; 1.0942x over previous
//
#include <hip/hip_runtime.h>
#include <hip/hip_bf16.h>

#define NND 2048
#define BBATCH 4
#define SS 1024
#define SFZ 384
#define IFZ 256
#define HH 8
#define AA 64
#define HA 512
#define ABLK 12   // 64-node x-blocks per batch (768-node capacity, 13 sigma)
#define NGRP 4    // 16-node groups per x-block
#define NSPL 8    // S-splits in attention
#define ATTN_BLKS (BBATCH * ABLK * 16)   // 768 attention blocks
#define LOGIT_BLKS (BBATCH * ABLK * 2)   // 96 logits blocks appended

typedef __attribute__((ext_vector_type(8))) short bf16x8;
typedef __attribute__((ext_vector_type(4))) float f32x4;
typedef __attribute__((ext_vector_type(2))) unsigned int u32x2;

__device__ __forceinline__ unsigned short f2bf(float f) {
    union { float f; unsigned u; } a; a.f = f;
    unsigned r = a.u + 0x7fffu + ((a.u >> 16) & 1u);
    return (unsigned short)(r >> 16);
}
__device__ __forceinline__ float bf2f(unsigned short u) {
    return __uint_as_float((unsigned)u << 16);
}

__device__ __forceinline__ bf16x8 cvt8(const float* __restrict__ p) {
    const float4 f0 = *(const float4*)p;
    const float4 f1 = *(const float4*)(p + 4);
    bf16x8 o;
    o[0] = (short)f2bf(f0.x); o[1] = (short)f2bf(f0.y);
    o[2] = (short)f2bf(f0.z); o[3] = (short)f2bf(f0.w);
    o[4] = (short)f2bf(f1.x); o[5] = (short)f2bf(f1.y);
    o[6] = (short)f2bf(f1.z); o[7] = (short)f2bf(f1.w);
    return o;
}

// --- forced-issue async loads (asm volatile preserves issue order) ---
__device__ __forceinline__ bf16x8 gld16(const unsigned short* p) {
    bf16x8 r;
    asm volatile("global_load_dwordx4 %0, %1, off" : "=&v"(r) : "v"(p));
    return r;
}
__device__ __forceinline__ f32x4 gldf4(const float* p) {
    f32x4 r;
    asm volatile("global_load_dwordx4 %0, %1, off" : "=&v"(r) : "v"(p));
    return r;
}
__device__ __forceinline__ u32x2 gld8(const unsigned short* p) {
    u32x2 r;
    asm volatile("global_load_dwordx2 %0, %1, off" : "=&v"(r) : "v"(p));
    return r;
}
#define VMWAIT0() do { \
    asm volatile("s_waitcnt vmcnt(0)" ::: "memory"); \
    __builtin_amdgcn_sched_barrier(0); \
} while (0)

// ---------------------------------------------------------------------------
// Kernel P: prep. Blocks 0..191: weight transposes fp32->bf16.
// Block 192: detect mask/batch dtype -> mask_f, seg.
// ---------------------------------------------------------------------------
__device__ __forceinline__ void tile_transpose(
    const float* __restrict__ src, unsigned short* __restrict__ dst,
    int K, int N, int kt, int nt, int t)
{
    __shared__ unsigned short tile[64][65];
    const int k0 = kt * 64, n0 = nt * 64;
    const int tr = t >> 6, tc = t & 63;
    #pragma unroll
    for (int r = 0; r < 16; ++r)
        tile[tr + r*4][tc] = f2bf(src[(size_t)(k0 + tr + r*4) * N + n0 + tc]);
    __syncthreads();
    #pragma unroll
    for (int r = 0; r < 16; ++r)
        dst[(size_t)(n0 + tr + r*4) * K + k0 + tc] = tile[tc][tr + r*4];
}

__global__ __launch_bounds__(256) void prep_kernel(
    const float* __restrict__ Wk, const float* __restrict__ Wv,
    const float* __restrict__ Wq, const float* __restrict__ Wg,
    const float* __restrict__ Wback,
    const void* __restrict__ mask_raw, const void* __restrict__ batch_raw,
    unsigned short* __restrict__ WkT, unsigned short* __restrict__ WvT,
    unsigned short* __restrict__ WqT, unsigned short* __restrict__ WgT,
    unsigned short* __restrict__ WbackT,
    float* __restrict__ mask_f, int* __restrict__ seg)
{
    const int bx = blockIdx.x, t = threadIdx.x;
    if (bx < 48)  { tile_transpose(Wk, WkT, SFZ, HA, bx/8, bx%8, t); return; }
    if (bx < 96)  { const int i = bx-48;  tile_transpose(Wv, WvT, SFZ, HA, i/8, i%8, t); return; }
    if (bx < 128) { const int i = bx-96;  tile_transpose(Wq, WqT, IFZ, HA, i/8, i%8, t); return; }
    if (bx < 160) { const int i = bx-128; tile_transpose(Wg, WgT, IFZ, HA, i/8, i%8, t); return; }
    if (bx < 192) { const int i = bx-160; tile_transpose(Wback, WbackT, HA, IFZ, i/4, i%4, t); return; }
    __shared__ int fl[4];
    __shared__ int fb;
    __shared__ int cnt[4];
    if (t < 4) { fl[t] = 0; cnt[t] = 0; }
    if (t == 0) fb = 0;
    __syncthreads();
    const unsigned char*  mb = (const unsigned char*)mask_raw;
    const unsigned short* mh = (const unsigned short*)mask_raw;
    const unsigned int*   mw = (const unsigned int*)mask_raw;
    int f0 = 0, f1 = 0, f2 = 0, f3 = 0;
    for (int i = t; i < 2048; i += 256) {
        unsigned short h = mh[i];
        if (h == 0x3f80u) f0 = 1;
        if ((i & 1) == 0 && h != 0) f1 = 1;
    }
    for (int i = t; i < 4096; i += 256)
        if ((i & 3) != 0 && mb[i] != 0) f2 = 1;
    for (int i = t; i < 1024; i += 256)
        if ((i & 1) != 0 && mw[i] != 0) f3 = 1;
    const int* bw = (const int*)batch_raw;
    int f4 = 0;
    for (int i = t + 1; i < 2048; i += 256)
        if (bw[i] < bw[i-1]) f4 = 1;
    if (f0) atomicOr(&fl[0], 1);
    if (f1) atomicOr(&fl[1], 1);
    if (f2) atomicOr(&fl[2], 1);
    if (f3) atomicOr(&fl[3], 1);
    if (f4) atomicOr(&fb, 1);
    __syncthreads();
    int mode;
    if (fl[0])      mode = fl[1] ? 1 : 0;
    else if (fl[2]) mode = 2;
    else if (fl[3]) mode = 3;
    else            mode = 4;
    for (int s = t; s < BBATCH*SS; s += 256) {
        int m;
        switch (mode) {
            case 0:  m = (mw[s]   != 0); break;
            case 1:  m = (mh[s]   != 0); break;
            case 2:  m = (mb[s]   != 0); break;
            case 3:  m = (mw[s]   != 0); break;
            default: m = (mw[2*s] != 0); break;
        }
        mask_f[s] = m ? 1.0f : 0.0f;
    }
    const int b64 = fb;
    for (int i = t; i < NND; i += 256) {
        const int bv = (b64 ? bw[2*i] : bw[i]) & 3;
        atomicAdd(&cnt[bv], 1);
    }
    __syncthreads();
    if (t == 0) {
        int s = 0;
        for (int b = 0; b < 4; ++b) { seg[2*b] = s; s += cnt[b]; seg[2*b+1] = s; }
    }
}

// ---------------------------------------------------------------------------
// Kernel 1: fused MFMA projections, WEIGHT-REUSE remap.
// [0,256): k/v. Block = 64 emb rows x 128 cols (rowblk = bx>>2, colblk = bx&3).
//   All 4 waves read the SAME weight columns (wave-uniform addresses -> L1/L2
//   reuse), each wave owns 16 rows. Weight traffic drops ~5x vs 16-row blocks.
// [256,384): q/gate. Block = 64 x rows x 128 cols (i>>2, i&3), same scheme.
// Burst/MFMA inner code identical to the R8-verified version.
// ---------------------------------------------------------------------------
__global__ __launch_bounds__(256, 2) void proj_mfma(
    const float* __restrict__ emb, const float* __restrict__ x,
    const unsigned short* __restrict__ WkT, const unsigned short* __restrict__ WvT,
    const unsigned short* __restrict__ WqT, const unsigned short* __restrict__ WgT,
    const float* __restrict__ bg,
    unsigned short* __restrict__ k_blk, unsigned short* __restrict__ vT_bf,
    unsigned short* __restrict__ q_bf, float* __restrict__ gate_ws)
{
    __shared__ unsigned short v_l[64][136];   // 17.4 KB (k/v blocks only)
    const int t = threadIdx.x, w = t >> 6, lane = t & 63;
    const int m16 = lane & 15, quad = lane >> 4;
    const int bx = blockIdx.x;
    if (bx < 256) {
        const int rowblk = bx >> 2, colblk = bx & 3;
        const int r0 = rowblk * 64;               // block row base (64 | 1024)
        const int rw = r0 + w * 16;               // wave's rows
        const int b = r0 >> 10, srow = r0 & (SS - 1);
        const int srw = rw & (SS - 1);
        const float* ap = emb + (size_t)(rw + m16) * SFZ + quad * 8;
        bf16x8 af[12];
        #pragma unroll
        for (int j = 0; j < 12; ++j) af[j] = cvt8(ap + j * 32);
        #pragma unroll
        for (int tensor = 0; tensor < 2; ++tensor) {
            const unsigned short* Wt = tensor ? WvT : WkT;
            #pragma unroll
            for (int g = 0; g < 2; ++g) {
                const int n0g = colblk * 128 + g * 64;   // wave-uniform cols
                const unsigned short* bp0 = Wt + (size_t)(n0g +  0 + m16) * SFZ + quad * 8;
                const unsigned short* bp1 = Wt + (size_t)(n0g + 16 + m16) * SFZ + quad * 8;
                const unsigned short* bp2 = Wt + (size_t)(n0g + 32 + m16) * SFZ + quad * 8;
                const unsigned short* bp3 = Wt + (size_t)(n0g + 48 + m16) * SFZ + quad * 8;
                f32x4 a0 = (f32x4){0.f, 0.f, 0.f, 0.f};
                f32x4 a1 = a0, a2 = a0, a3 = a0;
                bf16x8 wb[24];
                #pragma unroll
                for (int j = 0; j < 6; ++j) {
                    wb[j*4+0] = gld16(bp0 + j * 32);
                    wb[j*4+1] = gld16(bp1 + j * 32);
                    wb[j*4+2] = gld16(bp2 + j * 32);
                    wb[j*4+3] = gld16(bp3 + j * 32);
                }
                VMWAIT0();
                #pragma unroll
                for (int j = 0; j < 6; ++j) {
                    a0 = __builtin_amdgcn_mfma_f32_16x16x32_bf16(af[j], wb[j*4+0], a0, 0, 0, 0);
                    a1 = __builtin_amdgcn_mfma_f32_16x16x32_bf16(af[j], wb[j*4+1], a1, 0, 0, 0);
                    a2 = __builtin_amdgcn_mfma_f32_16x16x32_bf16(af[j], wb[j*4+2], a2, 0, 0, 0);
                    a3 = __builtin_amdgcn_mfma_f32_16x16x32_bf16(af[j], wb[j*4+3], a3, 0, 0, 0);
                }
                #pragma unroll
                for (int j = 6; j < 12; ++j) {
                    wb[(j-6)*4+0] = gld16(bp0 + j * 32);
                    wb[(j-6)*4+1] = gld16(bp1 + j * 32);
                    wb[(j-6)*4+2] = gld16(bp2 + j * 32);
                    wb[(j-6)*4+3] = gld16(bp3 + j * 32);
                }
                VMWAIT0();
                #pragma unroll
                for (int j = 6; j < 12; ++j) {
                    a0 = __builtin_amdgcn_mfma_f32_16x16x32_bf16(af[j], wb[(j-6)*4+0], a0, 0, 0, 0);
                    a1 = __builtin_amdgcn_mfma_f32_16x16x32_bf16(af[j], wb[(j-6)*4+1], a1, 0, 0, 0);
                    a2 = __builtin_amdgcn_mfma_f32_16x16x32_bf16(af[j], wb[(j-6)*4+2], a2, 0, 0, 0);
                    a3 = __builtin_amdgcn_mfma_f32_16x16x32_bf16(af[j], wb[(j-6)*4+3], a3, 0, 0, 0);
                }
                f32x4 dd[4] = {a0, a1, a2, a3};
                if (tensor == 0) {
                    #pragma unroll
                    for (int u = 0; u < 4; ++u) {
                        const int n0 = n0g + u * 16;
                        const int head = n0 >> 6, coff = (n0 & 63) + m16;
                        unsigned short* kb = k_blk + (((size_t)(b * HH + head)) * SS) * 64 + coff;
                        #pragma unroll
                        for (int r = 0; r < 4; ++r)
                            kb[(size_t)(srw + quad * 4 + r) * 64] = f2bf(dd[u][r]);
                    }
                } else {
                    #pragma unroll
                    for (int u = 0; u < 4; ++u) {
                        const int c0 = g * 64 + u * 16 + m16;   // local col in [0,128)
                        #pragma unroll
                        for (int r = 0; r < 4; ++r)
                            v_l[w * 16 + quad * 4 + r][c0] = f2bf(dd[u][r]);
                    }
                }
            }
        }
        __syncthreads();
        // vT[b][colblk*128+col][srow..srow+64): column gather, 64B stores.
        {
            const int col = t & 127, half = t >> 7;   // 256 thr = 128 cols x 2 halves
            unsigned short tmp[32];
            #pragma unroll
            for (int s = 0; s < 32; ++s) tmp[s] = v_l[half * 32 + s][col];
            unsigned short* dst = vT_bf + ((size_t)b * HA + colblk * 128 + col) * SS
                                        + srow + half * 32;
            *(uint4*)dst        = ((const uint4*)tmp)[0];
            *(uint4*)(dst + 8)  = ((const uint4*)tmp)[1];
            *(uint4*)(dst + 16) = ((const uint4*)tmp)[2];
            *(uint4*)(dst + 24) = ((const uint4*)tmp)[3];
        }
    } else {
        const int i = bx - 256;
        const int rowblk = i >> 2, colblk = i & 3;
        const int r0 = rowblk * 64;
        const int rw = r0 + w * 16;
        const float* ap = x + (size_t)(rw + m16) * IFZ + quad * 8;
        bf16x8 af[8];
        #pragma unroll
        for (int j = 0; j < 8; ++j) af[j] = cvt8(ap + j * 32);
        #pragma unroll
        for (int tensor = 0; tensor < 2; ++tensor) {
            const unsigned short* Wt = tensor ? WgT : WqT;
            #pragma unroll
            for (int g = 0; g < 2; ++g) {
                const int n0g = colblk * 128 + g * 64;   // wave-uniform cols
                const unsigned short* bp0 = Wt + (size_t)(n0g +  0 + m16) * IFZ + quad * 8;
                const unsigned short* bp1 = Wt + (size_t)(n0g + 16 + m16) * IFZ + quad * 8;
                const unsigned short* bp2 = Wt + (size_t)(n0g + 32 + m16) * IFZ + quad * 8;
                const unsigned short* bp3 = Wt + (size_t)(n0g + 48 + m16) * IFZ + quad * 8;
                bf16x8 wb[32];
                #pragma unroll
                for (int j = 0; j < 8; ++j) {
                    wb[j*4+0] = gld16(bp0 + j * 32);
                    wb[j*4+1] = gld16(bp1 + j * 32);
                    wb[j*4+2] = gld16(bp2 + j * 32);
                    wb[j*4+3] = gld16(bp3 + j * 32);
                }
                VMWAIT0();
                f32x4 a0 = (f32x4){0.f, 0.f, 0.f, 0.f};
                f32x4 a1 = a0, a2 = a0, a3 = a0;
                #pragma unroll
                for (int j = 0; j < 8; ++j) {
                    a0 = __builtin_amdgcn_mfma_f32_16x16x32_bf16(af[j], wb[j*4+0], a0, 0, 0, 0);
                    a1 = __builtin_amdgcn_mfma_f32_16x16x32_bf16(af[j], wb[j*4+1], a1, 0, 0, 0);
                    a2 = __builtin_amdgcn_mfma_f32_16x16x32_bf16(af[j], wb[j*4+2], a2, 0, 0, 0);
                    a3 = __builtin_amdgcn_mfma_f32_16x16x32_bf16(af[j], wb[j*4+3], a3, 0, 0, 0);
                }
                f32x4 dd[4] = {a0, a1, a2, a3};
                if (tensor == 0) {
                    #pragma unroll
                    for (int u = 0; u < 4; ++u) {
                        const int n0 = n0g + u * 16;
                        #pragma unroll
                        for (int r = 0; r < 4; ++r)
                            q_bf[(size_t)(rw + quad * 4 + r) * HA + n0 + m16] = f2bf(dd[u][r]);
                    }
                } else {
                    #pragma unroll
                    for (int u = 0; u < 4; ++u) {
                        const int n0 = n0g + u * 16;
                        const float bgv = bg[n0 + m16];
                        #pragma unroll
                        for (int r = 0; r < 4; ++r)
                            gate_ws[(size_t)(rw + quad * 4 + r) * HA + n0 + m16] =
                                1.f / (1.f + __expf(-(dd[u][r] + bgv)));
                    }
                }
            }
        }
    }
}

// ---------------------------------------------------------------------------
// Kernel 3: flash attention (barrier-free) + appended logits blocks.
// (identical to R8 — best measured configuration)
// ---------------------------------------------------------------------------
__global__ __launch_bounds__(256, 2) void attn_kernel(
    const unsigned short* __restrict__ k_blk, const unsigned short* __restrict__ vT_bf,
    const unsigned short* __restrict__ q_bf, const float* __restrict__ mask_f,
    const int* __restrict__ seg, unsigned short* __restrict__ part_O,
    float2* __restrict__ part_ml, float* __restrict__ out_logits)
{
    __shared__ unsigned short P_lds[4][16][136];   // 17.4 KB
    const int bid = blockIdx.x;
    const int t = threadIdx.x;
    const int w = t >> 6, lane = t & 63;
    const int m16 = lane & 15, quad = lane >> 4;

    if (bid >= ATTN_BLKS) {
        // ================== logits role ==================
        const int lid = bid - ATTN_BLKS;          // [0,96)
        const int b = lid / 24;
        const int rem = lid % 24;
        const int xblk = rem >> 1;                // [0,12)
        const int spair = rem & 1;
        const int s0 = (spair * 4 + w) * 128;
        const int nbase = seg[2*b] + xblk * 64;
        const int nend  = seg[2*b + 1];
        if (nbase >= nend) return;
        const unsigned short* kb0 = k_blk + ((size_t)(b * HH + 0)) * SS * 64;
        const unsigned short* kb1 = k_blk + ((size_t)(b * HH + 1)) * SS * 64;
        bf16x8 k0[16], k1[16];
        #pragma unroll
        for (int st = 0; st < 8; ++st) {
            const unsigned short* kp0 = kb0 + (size_t)(s0 + st * 16 + m16) * 64 + quad * 8;
            const unsigned short* kp1 = kb1 + (size_t)(s0 + st * 16 + m16) * 64 + quad * 8;
            k0[2*st]   = gld16(kp0);
            k0[2*st+1] = gld16(kp0 + 32);
            k1[2*st]   = gld16(kp1);
            k1[2*st+1] = gld16(kp1 + 32);
        }
        VMWAIT0();
        for (int g = 0; g < NGRP; ++g) {
            const int n0g = nbase + g * 16;
            if (n0g >= nend) break;
            const int nvalid = min(16, nend - n0g);
            int nq = n0g + m16; if (nq >= nend) nq = nend - 1;
            const unsigned short* qp = q_bf + (size_t)nq * HA + quad * 8;
            const bf16x8 q0a = gld16(qp);
            const bf16x8 q0b = gld16(qp + 32);
            const bf16x8 q1a = gld16(qp + 64);
            const bf16x8 q1b = gld16(qp + 96);
            VMWAIT0();
            #pragma unroll
            for (int st = 0; st < 8; ++st) {
                f32x4 acc = (f32x4){0.f, 0.f, 0.f, 0.f};
                acc = __builtin_amdgcn_mfma_f32_16x16x32_bf16(q0a, k0[2*st],   acc, 0, 0, 0);
                acc = __builtin_amdgcn_mfma_f32_16x16x32_bf16(q0b, k0[2*st+1], acc, 0, 0, 0);
                acc = __builtin_amdgcn_mfma_f32_16x16x32_bf16(q1a, k1[2*st],   acc, 0, 0, 0);
                acc = __builtin_amdgcn_mfma_f32_16x16x32_bf16(q1b, k1[2*st+1], acc, 0, 0, 0);
                #pragma unroll
                for (int r = 0; r < 4; ++r) {
                    const int row = quad * 4 + r;
                    if (row < nvalid)
                        out_logits[(size_t)(n0g + row) * SS + s0 + st * 16 + m16] =
                            acc[r] * 0.125f;
                }
            }
        }
        return;
    }

    // ================== attention role (barrier-free) ==================
    const int xcd = bid & 7;
    const int b   = xcd >> 1;
    const int idx = (bid >> 3) * 2 + (xcd & 1);   // [0,192)
    const int z    = idx & 15;
    const int xblk = idx >> 4;                    // [0,12)
    const int hz    = z >> 3;
    const int split = z & 7;
    const int nbase = seg[2*b] + xblk * (16 * NGRP);
    const int nend  = seg[2*b + 1];
    if (nbase >= nend) return;

    const int h = hz * 4 + w;
    const int s0 = split * 128;

    const unsigned short* kb = k_blk + ((size_t)(b * HH + h)) * SS * 64;
    const unsigned short* vb = vT_bf + ((size_t)b * HA + h * AA) * SS;
    const unsigned short* qbase = q_bf + (size_t)h * AA + quad * 8;
    unsigned short (*Pw)[136] = P_lds[w];

    // ---- prologue burst: K(16) + mask(8) + q0(2) ----
    bf16x8 kf[16];
    #pragma unroll
    for (int st = 0; st < 8; ++st) {
        const unsigned short* kp = kb + (size_t)(s0 + st * 16 + m16) * 64 + quad * 8;
        kf[2*st]   = gld16(kp);
        kf[2*st+1] = gld16(kp + 32);
    }
    f32x4 mkv[8];
    #pragma unroll
    for (int st = 0; st < 8; ++st)
        mkv[st] = gldf4(mask_f + b * SS + s0 + st * 16 + quad * 4);
    int nq0 = nbase + m16; if (nq0 >= nend) nq0 = nend - 1;
    bf16x8 qc0 = gld16(qbase + (size_t)nq0 * HA);
    bf16x8 qc1 = gld16(qbase + (size_t)nq0 * HA + 32);
    VMWAIT0();
    // ---- per-lane mask bitmask: bit (st*4+r) <-> s = st*16 + quad*4 + r ----
    unsigned bm = 0u;
    #pragma unroll
    for (int st = 0; st < 8; ++st)
        #pragma unroll
        for (int r = 0; r < 4; ++r)
            if (mkv[st][r] > 0.5f) bm |= (1u << (st * 4 + r));

    bf16x8 qn0 = qc0, qn1 = qc1;
    for (int g = 0; g < NGRP; ++g) {
        const int n0g = nbase + g * 16;
        if (n0g >= nend) break;                     // block-uniform
        const int nvalid = min(16, nend - n0g);

        // ---- QK^T swapped: C[row=s(st*16+quad*4+r)][col=node(m16)] ----
        f32x4 d[8];
        #pragma unroll
        for (int st = 0; st < 8; ++st) {
            f32x4 acc = (f32x4){0.f, 0.f, 0.f, 0.f};
            acc = __builtin_amdgcn_mfma_f32_16x16x32_bf16(kf[2*st],   qc0, acc, 0, 0, 0);
            acc = __builtin_amdgcn_mfma_f32_16x16x32_bf16(kf[2*st+1], qc1, acc, 0, 0, 0);
            #pragma unroll
            for (int r = 0; r < 4; ++r) acc[r] *= 0.125f;
            d[st] = acc;
        }
        // ---- issue V burst + next-q; softmax hides their latency ----
        bf16x8 vf[16];
        #pragma unroll
        for (int sub = 0; sub < 4; ++sub) {
            const unsigned short* vp0 = vb + (size_t)m16 * SS + s0 + sub * 32 + quad * 8;
            #pragma unroll
            for (int a = 0; a < 4; ++a)
                vf[sub*4+a] = gld16(vp0 + (size_t)(a * 16) * SS);
        }
        if (g + 1 < NGRP && nbase + (g + 1) * 16 < nend) {
            int nqn = nbase + (g + 1) * 16 + m16; if (nqn >= nend) nqn = nend - 1;
            qn0 = gld16(qbase + (size_t)nqn * HA);
            qn1 = gld16(qbase + (size_t)nqn * HA + 32);
        }
        __builtin_amdgcn_sched_barrier(0);

        // ---- lane-local masked softmax (node = m16, per lane) ----
        #pragma unroll
        for (int st = 0; st < 8; ++st)
            #pragma unroll
            for (int r = 0; r < 4; ++r)
                if (!((bm >> (st * 4 + r)) & 1u)) d[st][r] = -3.0e38f;
        float mx = -3.0e38f;
        #pragma unroll
        for (int st = 0; st < 8; ++st) {
            float a = fmaxf(fmaxf(d[st][0], d[st][1]), fmaxf(d[st][2], d[st][3]));
            mx = fmaxf(mx, a);
        }
        mx = fmaxf(mx, __shfl_xor(mx, 16));
        mx = fmaxf(mx, __shfl_xor(mx, 32));
        mx = fmaxf(mx, -1.0e30f);      // all-masked rows -> exp underflow -> l=0
        float cs = 0.f;
        #pragma unroll
        for (int st = 0; st < 8; ++st)
            #pragma unroll
            for (int r = 0; r < 4; ++r) {
                const float e = __expf(d[st][r] - mx);
                d[st][r] = e;
                cs += e;
            }
        cs += __shfl_xor(cs, 16);
        cs += __shfl_xor(cs, 32);
        // ---- P -> LDS: lane owns node m16, 4 contiguous bf16 per st ----
        #pragma unroll
        for (int st = 0; st < 8; ++st) {
            ushort4 pk;
            pk.x = f2bf(d[st][0]); pk.y = f2bf(d[st][1]);
            pk.z = f2bf(d[st][2]); pk.w = f2bf(d[st][3]);
            *(ushort4*)&Pw[m16][st * 16 + quad * 4] = pk;
        }
        bf16x8 pa[4];
        #pragma unroll
        for (int sub = 0; sub < 4; ++sub)
            pa[sub] = *(const bf16x8*)&Pw[m16][sub * 32 + quad * 8];
        // ---- wait V (stores from prior group long retired); PV ----
        VMWAIT0();
        f32x4 facc[4];
        #pragma unroll
        for (int a = 0; a < 4; ++a) facc[a] = (f32x4){0.f, 0.f, 0.f, 0.f};
        #pragma unroll
        for (int sub = 0; sub < 4; ++sub) {
            #pragma unroll
            for (int a = 0; a < 4; ++a)
                facc[a] = __builtin_amdgcn_mfma_f32_16x16x32_bf16(pa[sub], vf[sub*4+a], facc[a], 0, 0, 0);
        }
        // ---- epilogue: partial O (C row=node) + per-node (m,l) ----
        unsigned short* po = part_O + (size_t)split * NND * HA;
        #pragma unroll
        for (int a = 0; a < 4; ++a)
            #pragma unroll
            for (int r = 0; r < 4; ++r) {
                const int row = quad * 4 + r;
                if (row < nvalid)
                    po[(size_t)(n0g + row) * HA + h * AA + a * 16 + m16] = f2bf(facc[a][r]);
            }
        if (quad == 0 && m16 < nvalid)
            part_ml[(size_t)split * NND * HH + (size_t)(n0g + m16) * HH + h] =
                make_float2(mx, cs);
        qc0 = qn0; qc1 = qn1;
    }
}

// ---------------------------------------------------------------------------
// Kernel 4: fused combine(8 splits) + gate mul + Wback MFMA + residual + LN.
// (identical to R8)
// ---------------------------------------------------------------------------
__global__ __launch_bounds__(256, 2) void back_ln_fused(
    const unsigned short* __restrict__ part_O, const float2* __restrict__ part_ml,
    const float* __restrict__ gate_ws, const unsigned short* __restrict__ WbackT,
    const float* __restrict__ x, const float* __restrict__ bback,
    const float* __restrict__ gamma, const float* __restrict__ beta,
    float* __restrict__ out)
{
    __shared__ float coef[NSPL][8][8];
    __shared__ unsigned short gf_l[8][520];
    __shared__ float nl[8][260];
    const int t = threadIdx.x, w = t >> 6, lane = t & 63;
    const int m16 = lane & 15, quad = lane >> 4;
    const int r0 = blockIdx.x * 8;
    if (t < 64) {
        const int row = t >> 3, h = t & 7, n = r0 + row;
        float2 ml[NSPL];
        #pragma unroll
        for (int s = 0; s < NSPL; ++s)
            ml[s] = part_ml[(size_t)s * NND * HH + (size_t)n * HH + h];
        float M = -3.0e38f;
        #pragma unroll
        for (int s = 0; s < NSPL; ++s) M = fmaxf(M, ml[s].x);
        float L = 0.f;
        float e[NSPL];
        #pragma unroll
        for (int s = 0; s < NSPL; ++s) { e[s] = __expf(ml[s].x - M); L += ml[s].y * e[s]; }
        const float invL = 1.f / (L + 1e-9f);
        #pragma unroll
        for (int s = 0; s < NSPL; ++s) coef[s][row][h] = e[s] * invL;
    }
    u32x2 pvv[4][NSPL];
    f32x4 gv[4];
    #pragma unroll
    for (int it = 0; it < 4; ++it) {
        const int i = (t + it * 256) * 4;
        const int row = i >> 9, c = i & (HA - 1);
        const int n = r0 + row;
        #pragma unroll
        for (int s = 0; s < NSPL; ++s)
            pvv[it][s] = gld8(&part_O[(size_t)s * NND * HA + (size_t)n * HA + c]);
        gv[it] = gldf4(&gate_ws[(size_t)n * HA + c]);
    }
    __syncthreads();   // coef ready
    VMWAIT0();
    #pragma unroll
    for (int it = 0; it < 4; ++it) {
        const int i = (t + it * 256) * 4;
        const int row = i >> 9, c = i & (HA - 1), h = c >> 6;
        float4 o = make_float4(0.f, 0.f, 0.f, 0.f);
        #pragma unroll
        for (int s = 0; s < NSPL; ++s) {
            const float cf = coef[s][row][h];
            o.x = fmaf(bf2f((unsigned short)(pvv[it][s][0] & 0xffffu)), cf, o.x);
            o.y = fmaf(bf2f((unsigned short)(pvv[it][s][0] >> 16)),     cf, o.y);
            o.z = fmaf(bf2f((unsigned short)(pvv[it][s][1] & 0xffffu)), cf, o.z);
            o.w = fmaf(bf2f((unsigned short)(pvv[it][s][1] >> 16)),     cf, o.w);
        }
        ushort4 ob;
        ob.x = f2bf(gv[it][0] * o.x); ob.y = f2bf(gv[it][1] * o.y);
        ob.z = f2bf(gv[it][2] * o.z); ob.w = f2bf(gv[it][3] * o.w);
        *(ushort4*)&gf_l[row][c] = ob;
    }
    __syncthreads();
    bf16x8 af[16];
    #pragma unroll
    for (int j = 0; j < 16; ++j)
        af[j] = *(const bf16x8*)&gf_l[m16 & 7][quad * 8 + j * 32];
    const unsigned short* bq0 = WbackT + (size_t)(w * 64 +  0 + m16) * HA + quad * 8;
    const unsigned short* bq1 = WbackT + (size_t)(w * 64 + 16 + m16) * HA + quad * 8;
    const unsigned short* bq2 = WbackT + (size_t)(w * 64 + 32 + m16) * HA + quad * 8;
    const unsigned short* bq3 = WbackT + (size_t)(w * 64 + 48 + m16) * HA + quad * 8;
    f32x4 a0 = (f32x4){0.f, 0.f, 0.f, 0.f};
    f32x4 a1 = a0, a2 = a0, a3 = a0;
    #pragma unroll
    for (int jb = 0; jb < 4; ++jb) {
        bf16x8 wb[16];
        #pragma unroll
        for (int j = 0; j < 4; ++j) {
            wb[j*4+0] = gld16(bq0 + (jb*4 + j) * 32);
            wb[j*4+1] = gld16(bq1 + (jb*4 + j) * 32);
            wb[j*4+2] = gld16(bq2 + (jb*4 + j) * 32);
            wb[j*4+3] = gld16(bq3 + (jb*4 + j) * 32);
        }
        VMWAIT0();
        #pragma unroll
        for (int j = 0; j < 4; ++j) {
            a0 = __builtin_amdgcn_mfma_f32_16x16x32_bf16(af[jb*4+j], wb[j*4+0], a0, 0, 0, 0);
            a1 = __builtin_amdgcn_mfma_f32_16x16x32_bf16(af[jb*4+j], wb[j*4+1], a1, 0, 0, 0);
            a2 = __builtin_amdgcn_mfma_f32_16x16x32_bf16(af[jb*4+j], wb[j*4+2], a2, 0, 0, 0);
            a3 = __builtin_amdgcn_mfma_f32_16x16x32_bf16(af[jb*4+j], wb[j*4+3], a3, 0, 0, 0);
        }
    }
    {
        f32x4 dd[4] = {a0, a1, a2, a3};
        #pragma unroll
        for (int u = 0; u < 4; ++u) {
            const int n0 = w * 64 + u * 16;
            const float bb = bback[n0 + m16];
            #pragma unroll
            for (int r = 0; r < 4; ++r) {
                const int rr = quad * 4 + r;
                if (rr < 8) nl[rr][n0 + m16] = dd[u][r] + bb;
            }
        }
    }
    __syncthreads();
    const int row = t >> 5, li = t & 31;
    const float* xr = x + (size_t)(r0 + row) * IFZ;
    float yv[8];
    float s1 = 0.f, s2 = 0.f;
    #pragma unroll
    for (int j = 0; j < 8; ++j) {
        const int c = li + j * 32;
        const float v = fmaf(1.41421356237309515f, xr[c], nl[row][c]);
        yv[j] = v; s1 += v; s2 += v * v;
    }
    #pragma unroll
    for (int off = 16; off >= 1; off >>= 1) {
        s1 += __shfl_xor(s1, off);
        s2 += __shfl_xor(s2, off);
    }
    const float mu  = s1 * (1.f / IFZ);
    const float var = s2 * (1.f / IFZ) - mu * mu;
    const float rv  = rsqrtf(var + 1e-5f);
    float* orow = out + (size_t)(r0 + row) * IFZ;
    #pragma unroll
    for (int j = 0; j < 8; ++j) {
        const int c = li + j * 32;
        orow[c] = (yv[j] - mu) * rv * gamma[c] + beta[c];
    }
}

extern "C" void kernel_launch(void* const* d_in, const int* in_sizes, int n_in,
                              void* d_out, int out_size, void* d_ws, size_t ws_size,
                              hipStream_t stream) {
    const float* x     = (const float*)d_in[0];
    const float* emb   = (const float*)d_in[1];
    const void*  mraw  = d_in[2];
    const void*  braw  = d_in[3];
    const float* Wq    = (const float*)d_in[4];
    const float* Wk    = (const float*)d_in[5];
    const float* Wv    = (const float*)d_in[6];
    const float* Wg    = (const float*)d_in[7];
    const float* bg    = (const float*)d_in[8];
    const float* Wback = (const float*)d_in[9];
    const float* bback = (const float*)d_in[10];
    const float* gamma = (const float*)d_in[11];
    const float* beta  = (const float*)d_in[12];

    char* ws = (char*)d_ws;
    const size_t MB = 1048576;
    size_t off = 0;
    float*          mask_f  = (float*)(ws + off);  off += 16384;
    int*            seg     = (int*)(ws + off);    off += 16384;
    unsigned short* WkT     = (unsigned short*)(ws + off); off += 393216;
    unsigned short* WvT     = (unsigned short*)(ws + off); off += 393216;
    unsigned short* WqT     = (unsigned short*)(ws + off); off += 262144;
    unsigned short* WgT     = (unsigned short*)(ws + off); off += 262144;
    unsigned short* WbackT  = (unsigned short*)(ws + off); off += 262144;
    unsigned short* k_blk   = (unsigned short*)(ws + off); off += 4*MB;
    unsigned short* vT_bf   = (unsigned short*)(ws + off); off += 4*MB;
    unsigned short* q_bf    = (unsigned short*)(ws + off); off += 2*MB;
    float*          gate_ws = (float*)(ws + off); off += 4*MB;
    unsigned short* part_O  = (unsigned short*)(ws + off); off += 16*MB;
    float2*         part_ml = (float2*)(ws + off); off += 1*MB;

    float* out        = (float*)d_out;
    float* out_logits = out + (size_t)NND * IFZ;

    hipLaunchKernelGGL(prep_kernel, dim3(193), dim3(256), 0, stream,
                       Wk, Wv, Wq, Wg, Wback, mraw, braw,
                       WkT, WvT, WqT, WgT, WbackT, mask_f, seg);
    hipLaunchKernelGGL(proj_mfma, dim3(384), dim3(256), 0, stream,
                       emb, x, WkT, WvT, WqT, WgT, bg, k_blk, vT_bf, q_bf, gate_ws);
    hipLaunchKernelGGL(attn_kernel, dim3(ATTN_BLKS + LOGIT_BLKS), dim3(256), 0, stream,
                       k_blk, vT_bf, q_bf, mask_f, seg, part_O, part_ml, out_logits);
    hipLaunchKernelGGL(back_ln_fused, dim3(NND / 8), dim3(256), 0, stream,
                       part_O, part_ml, gate_ws, WbackT, x, bback, gamma, beta, out);
}

// Round 12
// 181.887 us; speedup vs baseline: 1.1410x; 1.0427x over previous
//
#include <hip/hip_runtime.h>
#include <hip/hip_bf16.h>

#define NND 2048
#define BBATCH 4
#define SS 1024
#define SFZ 384
#define IFZ 256
#define HH 8
#define AA 64
#define HA 512
#define ABLK 12   // 64-node x-blocks per batch (768-node capacity, 13 sigma)
#define NGRP 4    // 16-node groups per x-block
#define NSPL 8    // S-splits in attention
#define ATTN_BLKS (BBATCH * ABLK * 16)   // 768 attention blocks
#define LOGIT_BLKS (BBATCH * ABLK * 2)   // 96 logits blocks (dispatched FIRST)

typedef __attribute__((ext_vector_type(8))) short bf16x8;
typedef __attribute__((ext_vector_type(4))) float f32x4;
typedef __attribute__((ext_vector_type(2))) unsigned int u32x2;

__device__ __forceinline__ unsigned short f2bf(float f) {
    union { float f; unsigned u; } a; a.f = f;
    unsigned r = a.u + 0x7fffu + ((a.u >> 16) & 1u);
    return (unsigned short)(r >> 16);
}
__device__ __forceinline__ float bf2f(unsigned short u) {
    return __uint_as_float((unsigned)u << 16);
}

__device__ __forceinline__ bf16x8 cvt8(const float* __restrict__ p) {
    const float4 f0 = *(const float4*)p;
    const float4 f1 = *(const float4*)(p + 4);
    bf16x8 o;
    o[0] = (short)f2bf(f0.x); o[1] = (short)f2bf(f0.y);
    o[2] = (short)f2bf(f0.z); o[3] = (short)f2bf(f0.w);
    o[4] = (short)f2bf(f1.x); o[5] = (short)f2bf(f1.y);
    o[6] = (short)f2bf(f1.z); o[7] = (short)f2bf(f1.w);
    return o;
}

// --- forced-issue async loads (asm volatile preserves issue order) ---
__device__ __forceinline__ bf16x8 gld16(const unsigned short* p) {
    bf16x8 r;
    asm volatile("global_load_dwordx4 %0, %1, off" : "=&v"(r) : "v"(p));
    return r;
}
__device__ __forceinline__ f32x4 gldf4(const float* p) {
    f32x4 r;
    asm volatile("global_load_dwordx4 %0, %1, off" : "=&v"(r) : "v"(p));
    return r;
}
__device__ __forceinline__ u32x2 gld8(const unsigned short* p) {
    u32x2 r;
    asm volatile("global_load_dwordx2 %0, %1, off" : "=&v"(r) : "v"(p));
    return r;
}
#define VMWAIT0() do { \
    asm volatile("s_waitcnt vmcnt(0)" ::: "memory"); \
    __builtin_amdgcn_sched_barrier(0); \
} while (0)

// ---------------------------------------------------------------------------
// Kernel P: prep. Blocks 0..191: weight transposes fp32->bf16.
// Block 192: detect mask/batch dtype -> mask_f, seg.
// ---------------------------------------------------------------------------
__device__ __forceinline__ void tile_transpose(
    const float* __restrict__ src, unsigned short* __restrict__ dst,
    int K, int N, int kt, int nt, int t)
{
    __shared__ unsigned short tile[64][65];
    const int k0 = kt * 64, n0 = nt * 64;
    const int tr = t >> 6, tc = t & 63;
    #pragma unroll
    for (int r = 0; r < 16; ++r)
        tile[tr + r*4][tc] = f2bf(src[(size_t)(k0 + tr + r*4) * N + n0 + tc]);
    __syncthreads();
    #pragma unroll
    for (int r = 0; r < 16; ++r)
        dst[(size_t)(n0 + tr + r*4) * K + k0 + tc] = tile[tc][tr + r*4];
}

__global__ __launch_bounds__(256) void prep_kernel(
    const float* __restrict__ Wk, const float* __restrict__ Wv,
    const float* __restrict__ Wq, const float* __restrict__ Wg,
    const float* __restrict__ Wback,
    const void* __restrict__ mask_raw, const void* __restrict__ batch_raw,
    unsigned short* __restrict__ WkT, unsigned short* __restrict__ WvT,
    unsigned short* __restrict__ WqT, unsigned short* __restrict__ WgT,
    unsigned short* __restrict__ WbackT,
    float* __restrict__ mask_f, int* __restrict__ seg)
{
    const int bx = blockIdx.x, t = threadIdx.x;
    if (bx < 48)  { tile_transpose(Wk, WkT, SFZ, HA, bx/8, bx%8, t); return; }
    if (bx < 96)  { const int i = bx-48;  tile_transpose(Wv, WvT, SFZ, HA, i/8, i%8, t); return; }
    if (bx < 128) { const int i = bx-96;  tile_transpose(Wq, WqT, IFZ, HA, i/8, i%8, t); return; }
    if (bx < 160) { const int i = bx-128; tile_transpose(Wg, WgT, IFZ, HA, i/8, i%8, t); return; }
    if (bx < 192) { const int i = bx-160; tile_transpose(Wback, WbackT, HA, IFZ, i/4, i%4, t); return; }
    __shared__ int fl[4];
    __shared__ int fb;
    __shared__ int cnt[4];
    if (t < 4) { fl[t] = 0; cnt[t] = 0; }
    if (t == 0) fb = 0;
    __syncthreads();
    const unsigned char*  mb = (const unsigned char*)mask_raw;
    const unsigned short* mh = (const unsigned short*)mask_raw;
    const unsigned int*   mw = (const unsigned int*)mask_raw;
    int f0 = 0, f1 = 0, f2 = 0, f3 = 0;
    for (int i = t; i < 2048; i += 256) {
        unsigned short h = mh[i];
        if (h == 0x3f80u) f0 = 1;
        if ((i & 1) == 0 && h != 0) f1 = 1;
    }
    for (int i = t; i < 4096; i += 256)
        if ((i & 3) != 0 && mb[i] != 0) f2 = 1;
    for (int i = t; i < 1024; i += 256)
        if ((i & 1) != 0 && mw[i] != 0) f3 = 1;
    const int* bw = (const int*)batch_raw;
    int f4 = 0;
    for (int i = t + 1; i < 2048; i += 256)
        if (bw[i] < bw[i-1]) f4 = 1;
    if (f0) atomicOr(&fl[0], 1);
    if (f1) atomicOr(&fl[1], 1);
    if (f2) atomicOr(&fl[2], 1);
    if (f3) atomicOr(&fl[3], 1);
    if (f4) atomicOr(&fb, 1);
    __syncthreads();
    int mode;
    if (fl[0])      mode = fl[1] ? 1 : 0;
    else if (fl[2]) mode = 2;
    else if (fl[3]) mode = 3;
    else            mode = 4;
    for (int s = t; s < BBATCH*SS; s += 256) {
        int m;
        switch (mode) {
            case 0:  m = (mw[s]   != 0); break;
            case 1:  m = (mh[s]   != 0); break;
            case 2:  m = (mb[s]   != 0); break;
            case 3:  m = (mw[s]   != 0); break;
            default: m = (mw[2*s] != 0); break;
        }
        mask_f[s] = m ? 1.0f : 0.0f;
    }
    const int b64 = fb;
    for (int i = t; i < NND; i += 256) {
        const int bv = (b64 ? bw[2*i] : bw[i]) & 3;
        atomicAdd(&cnt[bv], 1);
    }
    __syncthreads();
    if (t == 0) {
        int s = 0;
        for (int b = 0; b < 4; ++b) { seg[2*b] = s; s += cnt[b]; seg[2*b+1] = s; }
    }
}

// ---------------------------------------------------------------------------
// Kernel 1: fused MFMA projections (merged k+v / q+gate, R8 form).
// ---------------------------------------------------------------------------
__global__ __launch_bounds__(256, 2) void proj_mfma(
    const float* __restrict__ emb, const float* __restrict__ x,
    const unsigned short* __restrict__ WkT, const unsigned short* __restrict__ WvT,
    const unsigned short* __restrict__ WqT, const unsigned short* __restrict__ WgT,
    const float* __restrict__ bg,
    unsigned short* __restrict__ k_blk, unsigned short* __restrict__ vT_bf,
    unsigned short* __restrict__ q_bf, float* __restrict__ gate_ws)
{
    __shared__ unsigned short v_l[16][520];   // 16.6 KB
    const int t = threadIdx.x, w = t >> 6, lane = t & 63;
    const int m16 = lane & 15, quad = lane >> 4;
    const int bx = blockIdx.x;
    if (bx < 256) {
        const int r0 = bx * 16;
        const int b = r0 >> 10, srow = r0 & (SS - 1);
        const float* ap = emb + (size_t)(r0 + m16) * SFZ + quad * 8;
        bf16x8 af[12];
        #pragma unroll
        for (int j = 0; j < 12; ++j) af[j] = cvt8(ap + j * 32);
        #pragma unroll
        for (int tensor = 0; tensor < 2; ++tensor) {
            const unsigned short* Wt = tensor ? WvT : WkT;
            #pragma unroll
            for (int g = 0; g < 2; ++g) {
                const int n0g = w * 128 + g * 64;
                const unsigned short* bp0 = Wt + (size_t)(n0g +  0 + m16) * SFZ + quad * 8;
                const unsigned short* bp1 = Wt + (size_t)(n0g + 16 + m16) * SFZ + quad * 8;
                const unsigned short* bp2 = Wt + (size_t)(n0g + 32 + m16) * SFZ + quad * 8;
                const unsigned short* bp3 = Wt + (size_t)(n0g + 48 + m16) * SFZ + quad * 8;
                f32x4 a0 = (f32x4){0.f, 0.f, 0.f, 0.f};
                f32x4 a1 = a0, a2 = a0, a3 = a0;
                bf16x8 wb[24];
                #pragma unroll
                for (int j = 0; j < 6; ++j) {
                    wb[j*4+0] = gld16(bp0 + j * 32);
                    wb[j*4+1] = gld16(bp1 + j * 32);
                    wb[j*4+2] = gld16(bp2 + j * 32);
                    wb[j*4+3] = gld16(bp3 + j * 32);
                }
                VMWAIT0();
                #pragma unroll
                for (int j = 0; j < 6; ++j) {
                    a0 = __builtin_amdgcn_mfma_f32_16x16x32_bf16(af[j], wb[j*4+0], a0, 0, 0, 0);
                    a1 = __builtin_amdgcn_mfma_f32_16x16x32_bf16(af[j], wb[j*4+1], a1, 0, 0, 0);
                    a2 = __builtin_amdgcn_mfma_f32_16x16x32_bf16(af[j], wb[j*4+2], a2, 0, 0, 0);
                    a3 = __builtin_amdgcn_mfma_f32_16x16x32_bf16(af[j], wb[j*4+3], a3, 0, 0, 0);
                }
                #pragma unroll
                for (int j = 6; j < 12; ++j) {
                    wb[(j-6)*4+0] = gld16(bp0 + j * 32);
                    wb[(j-6)*4+1] = gld16(bp1 + j * 32);
                    wb[(j-6)*4+2] = gld16(bp2 + j * 32);
                    wb[(j-6)*4+3] = gld16(bp3 + j * 32);
                }
                VMWAIT0();
                #pragma unroll
                for (int j = 6; j < 12; ++j) {
                    a0 = __builtin_amdgcn_mfma_f32_16x16x32_bf16(af[j], wb[(j-6)*4+0], a0, 0, 0, 0);
                    a1 = __builtin_amdgcn_mfma_f32_16x16x32_bf16(af[j], wb[(j-6)*4+1], a1, 0, 0, 0);
                    a2 = __builtin_amdgcn_mfma_f32_16x16x32_bf16(af[j], wb[(j-6)*4+2], a2, 0, 0, 0);
                    a3 = __builtin_amdgcn_mfma_f32_16x16x32_bf16(af[j], wb[(j-6)*4+3], a3, 0, 0, 0);
                }
                f32x4 dd[4] = {a0, a1, a2, a3};
                if (tensor == 0) {
                    #pragma unroll
                    for (int u = 0; u < 4; ++u) {
                        const int n0 = n0g + u * 16;
                        const int head = n0 >> 6, coff = (n0 & 63) + m16;
                        unsigned short* kb = k_blk + (((size_t)(b * HH + head)) * SS) * 64 + coff;
                        #pragma unroll
                        for (int r = 0; r < 4; ++r)
                            kb[(size_t)(srow + quad * 4 + r) * 64] = f2bf(dd[u][r]);
                    }
                } else {
                    #pragma unroll
                    for (int u = 0; u < 4; ++u) {
                        const int c0 = n0g + u * 16 + m16;
                        #pragma unroll
                        for (int r = 0; r < 4; ++r)
                            v_l[quad * 4 + r][c0] = f2bf(dd[u][r]);
                    }
                }
            }
        }
        __syncthreads();
        for (int c = t; c < HA; c += 256) {
            unsigned short tmp[16];
            #pragma unroll
            for (int s = 0; s < 16; ++s) tmp[s] = v_l[s][c];
            unsigned short* dst = vT_bf + ((size_t)b * HA + c) * SS + srow;
            *(uint4*)dst       = ((const uint4*)tmp)[0];
            *(uint4*)(dst + 8) = ((const uint4*)tmp)[1];
        }
    } else {
        const int i = bx - 256;
        const int r0 = (i >> 1) * 16;
        const int half = i & 1;
        const float* ap = x + (size_t)(r0 + m16) * IFZ + quad * 8;
        bf16x8 af[8];
        #pragma unroll
        for (int j = 0; j < 8; ++j) af[j] = cvt8(ap + j * 32);
        const int n0b = half * 256 + w * 64;
        #pragma unroll
        for (int tensor = 0; tensor < 2; ++tensor) {
            const unsigned short* Wt = tensor ? WgT : WqT;
            const unsigned short* bp0 = Wt + (size_t)(n0b +  0 + m16) * IFZ + quad * 8;
            const unsigned short* bp1 = Wt + (size_t)(n0b + 16 + m16) * IFZ + quad * 8;
            const unsigned short* bp2 = Wt + (size_t)(n0b + 32 + m16) * IFZ + quad * 8;
            const unsigned short* bp3 = Wt + (size_t)(n0b + 48 + m16) * IFZ + quad * 8;
            bf16x8 wb[32];
            #pragma unroll
            for (int j = 0; j < 8; ++j) {
                wb[j*4+0] = gld16(bp0 + j * 32);
                wb[j*4+1] = gld16(bp1 + j * 32);
                wb[j*4+2] = gld16(bp2 + j * 32);
                wb[j*4+3] = gld16(bp3 + j * 32);
            }
            VMWAIT0();
            f32x4 a0 = (f32x4){0.f, 0.f, 0.f, 0.f};
            f32x4 a1 = a0, a2 = a0, a3 = a0;
            #pragma unroll
            for (int j = 0; j < 8; ++j) {
                a0 = __builtin_amdgcn_mfma_f32_16x16x32_bf16(af[j], wb[j*4+0], a0, 0, 0, 0);
                a1 = __builtin_amdgcn_mfma_f32_16x16x32_bf16(af[j], wb[j*4+1], a1, 0, 0, 0);
                a2 = __builtin_amdgcn_mfma_f32_16x16x32_bf16(af[j], wb[j*4+2], a2, 0, 0, 0);
                a3 = __builtin_amdgcn_mfma_f32_16x16x32_bf16(af[j], wb[j*4+3], a3, 0, 0, 0);
            }
            f32x4 dd[4] = {a0, a1, a2, a3};
            if (tensor == 0) {
                #pragma unroll
                for (int u = 0; u < 4; ++u) {
                    const int n0 = n0b + u * 16;
                    #pragma unroll
                    for (int r = 0; r < 4; ++r)
                        q_bf[(size_t)(r0 + quad * 4 + r) * HA + n0 + m16] = f2bf(dd[u][r]);
                }
            } else {
                #pragma unroll
                for (int u = 0; u < 4; ++u) {
                    const int n0 = n0b + u * 16;
                    const float bgv = bg[n0 + m16];
                    #pragma unroll
                    for (int r = 0; r < 4; ++r)
                        gate_ws[(size_t)(r0 + quad * 4 + r) * HA + n0 + m16] =
                            1.f / (1.f + __expf(-(dd[u][r] + bgv)));
                }
            }
        }
    }
}

// ---------------------------------------------------------------------------
// Kernel 3: flash attention (barrier-free) + logits blocks DISPATCHED FIRST.
// launch_bounds(256,2): R11's (256,4) capped VGPR at 128 < asm-tied live
// ranges (kf+vf+q span vmcnt waits) -> spill wedge -> crash. Residency is
// resource-determined anyway (VGPR~112 allows 4 blocks/CU at (256,2)).
// Logits blocks are the longest-running -> schedule them first to avoid
// a makespan tail.
// ---------------------------------------------------------------------------
__global__ __launch_bounds__(256, 2) void attn_kernel(
    const unsigned short* __restrict__ k_blk, const unsigned short* __restrict__ vT_bf,
    const unsigned short* __restrict__ q_bf, const float* __restrict__ mask_f,
    const int* __restrict__ seg, unsigned short* __restrict__ part_O,
    float2* __restrict__ part_ml, float* __restrict__ out_logits)
{
    __shared__ unsigned short P_lds[4][16][136];   // 17.4 KB
    const int bid = blockIdx.x;
    const int t = threadIdx.x;
    const int w = t >> 6, lane = t & 63;
    const int m16 = lane & 15, quad = lane >> 4;

    if (bid < LOGIT_BLKS) {
        // ================== logits role (first in dispatch order) =========
        const int lid = bid;                      // [0,96)
        const int b = lid / 24;
        const int rem = lid % 24;
        const int xblk = rem >> 1;                // [0,12)
        const int spair = rem & 1;
        const int s0 = (spair * 4 + w) * 128;
        const int nbase = seg[2*b] + xblk * 64;
        const int nend  = seg[2*b + 1];
        if (nbase >= nend) return;
        const unsigned short* kb0 = k_blk + ((size_t)(b * HH + 0)) * SS * 64;
        const unsigned short* kb1 = k_blk + ((size_t)(b * HH + 1)) * SS * 64;
        bf16x8 k0[16], k1[16];
        #pragma unroll
        for (int st = 0; st < 8; ++st) {
            const unsigned short* kp0 = kb0 + (size_t)(s0 + st * 16 + m16) * 64 + quad * 8;
            const unsigned short* kp1 = kb1 + (size_t)(s0 + st * 16 + m16) * 64 + quad * 8;
            k0[2*st]   = gld16(kp0);
            k0[2*st+1] = gld16(kp0 + 32);
            k1[2*st]   = gld16(kp1);
            k1[2*st+1] = gld16(kp1 + 32);
        }
        VMWAIT0();
        for (int g = 0; g < NGRP; ++g) {
            const int n0g = nbase + g * 16;
            if (n0g >= nend) break;
            const int nvalid = min(16, nend - n0g);
            int nq = n0g + m16; if (nq >= nend) nq = nend - 1;
            const unsigned short* qp = q_bf + (size_t)nq * HA + quad * 8;
            const bf16x8 q0a = gld16(qp);
            const bf16x8 q0b = gld16(qp + 32);
            const bf16x8 q1a = gld16(qp + 64);
            const bf16x8 q1b = gld16(qp + 96);
            VMWAIT0();
            #pragma unroll
            for (int st = 0; st < 8; ++st) {
                f32x4 acc = (f32x4){0.f, 0.f, 0.f, 0.f};
                acc = __builtin_amdgcn_mfma_f32_16x16x32_bf16(q0a, k0[2*st],   acc, 0, 0, 0);
                acc = __builtin_amdgcn_mfma_f32_16x16x32_bf16(q0b, k0[2*st+1], acc, 0, 0, 0);
                acc = __builtin_amdgcn_mfma_f32_16x16x32_bf16(q1a, k1[2*st],   acc, 0, 0, 0);
                acc = __builtin_amdgcn_mfma_f32_16x16x32_bf16(q1b, k1[2*st+1], acc, 0, 0, 0);
                #pragma unroll
                for (int r = 0; r < 4; ++r) {
                    const int row = quad * 4 + r;
                    if (row < nvalid)
                        out_logits[(size_t)(n0g + row) * SS + s0 + st * 16 + m16] =
                            acc[r] * 0.125f;
                }
            }
        }
        return;
    }

    // ================== attention role (barrier-free) ==================
    const int abid = bid - LOGIT_BLKS;            // [0,768)
    const int xcd = abid & 7;
    const int b   = xcd >> 1;
    const int idx = (abid >> 3) * 2 + (xcd & 1);  // [0,192)
    const int z    = idx & 15;
    const int xblk = idx >> 4;                    // [0,12)
    const int hz    = z >> 3;
    const int split = z & 7;
    const int nbase = seg[2*b] + xblk * (16 * NGRP);
    const int nend  = seg[2*b + 1];
    if (nbase >= nend) return;

    const int h = hz * 4 + w;
    const int s0 = split * 128;

    const unsigned short* kb = k_blk + ((size_t)(b * HH + h)) * SS * 64;
    const unsigned short* vb = vT_bf + ((size_t)b * HA + h * AA) * SS;
    const unsigned short* qbase = q_bf + (size_t)h * AA + quad * 8;
    unsigned short (*Pw)[136] = P_lds[w];

    // ---- prologue burst: K(16) + mask(8) + q0(2) ----
    bf16x8 kf[16];
    #pragma unroll
    for (int st = 0; st < 8; ++st) {
        const unsigned short* kp = kb + (size_t)(s0 + st * 16 + m16) * 64 + quad * 8;
        kf[2*st]   = gld16(kp);
        kf[2*st+1] = gld16(kp + 32);
    }
    f32x4 mkv[8];
    #pragma unroll
    for (int st = 0; st < 8; ++st)
        mkv[st] = gldf4(mask_f + b * SS + s0 + st * 16 + quad * 4);
    int nq0 = nbase + m16; if (nq0 >= nend) nq0 = nend - 1;
    bf16x8 qc0 = gld16(qbase + (size_t)nq0 * HA);
    bf16x8 qc1 = gld16(qbase + (size_t)nq0 * HA + 32);
    VMWAIT0();
    // ---- per-lane mask bitmask: bit (st*4+r) <-> s = st*16 + quad*4 + r ----
    unsigned bm = 0u;
    #pragma unroll
    for (int st = 0; st < 8; ++st)
        #pragma unroll
        for (int r = 0; r < 4; ++r)
            if (mkv[st][r] > 0.5f) bm |= (1u << (st * 4 + r));

    bf16x8 qn0 = qc0, qn1 = qc1;
    for (int g = 0; g < NGRP; ++g) {
        const int n0g = nbase + g * 16;
        if (n0g >= nend) break;                     // block-uniform
        const int nvalid = min(16, nend - n0g);

        // ---- QK^T swapped: C[row=s(st*16+quad*4+r)][col=node(m16)] ----
        f32x4 d[8];
        #pragma unroll
        for (int st = 0; st < 8; ++st) {
            f32x4 acc = (f32x4){0.f, 0.f, 0.f, 0.f};
            acc = __builtin_amdgcn_mfma_f32_16x16x32_bf16(kf[2*st],   qc0, acc, 0, 0, 0);
            acc = __builtin_amdgcn_mfma_f32_16x16x32_bf16(kf[2*st+1], qc1, acc, 0, 0, 0);
            #pragma unroll
            for (int r = 0; r < 4; ++r) acc[r] *= 0.125f;
            d[st] = acc;
        }
        // ---- issue V burst + next-q; softmax hides their latency ----
        bf16x8 vf[16];
        #pragma unroll
        for (int sub = 0; sub < 4; ++sub) {
            const unsigned short* vp0 = vb + (size_t)m16 * SS + s0 + sub * 32 + quad * 8;
            #pragma unroll
            for (int a = 0; a < 4; ++a)
                vf[sub*4+a] = gld16(vp0 + (size_t)(a * 16) * SS);
        }
        if (g + 1 < NGRP && nbase + (g + 1) * 16 < nend) {
            int nqn = nbase + (g + 1) * 16 + m16; if (nqn >= nend) nqn = nend - 1;
            qn0 = gld16(qbase + (size_t)nqn * HA);
            qn1 = gld16(qbase + (size_t)nqn * HA + 32);
        }
        __builtin_amdgcn_sched_barrier(0);

        // ---- lane-local masked softmax (node = m16, per lane) ----
        #pragma unroll
        for (int st = 0; st < 8; ++st)
            #pragma unroll
            for (int r = 0; r < 4; ++r)
                if (!((bm >> (st * 4 + r)) & 1u)) d[st][r] = -3.0e38f;
        float mx = -3.0e38f;
        #pragma unroll
        for (int st = 0; st < 8; ++st) {
            float a = fmaxf(fmaxf(d[st][0], d[st][1]), fmaxf(d[st][2], d[st][3]));
            mx = fmaxf(mx, a);
        }
        mx = fmaxf(mx, __shfl_xor(mx, 16));
        mx = fmaxf(mx, __shfl_xor(mx, 32));
        mx = fmaxf(mx, -1.0e30f);      // all-masked rows -> exp underflow -> l=0
        float cs = 0.f;
        #pragma unroll
        for (int st = 0; st < 8; ++st)
            #pragma unroll
            for (int r = 0; r < 4; ++r) {
                const float e = __expf(d[st][r] - mx);
                d[st][r] = e;
                cs += e;
            }
        cs += __shfl_xor(cs, 16);
        cs += __shfl_xor(cs, 32);
        // ---- P -> LDS: lane owns node m16, 4 contiguous bf16 per st ----
        #pragma unroll
        for (int st = 0; st < 8; ++st) {
            ushort4 pk;
            pk.x = f2bf(d[st][0]); pk.y = f2bf(d[st][1]);
            pk.z = f2bf(d[st][2]); pk.w = f2bf(d[st][3]);
            *(ushort4*)&Pw[m16][st * 16 + quad * 4] = pk;
        }
        bf16x8 pa[4];
        #pragma unroll
        for (int sub = 0; sub < 4; ++sub)
            pa[sub] = *(const bf16x8*)&Pw[m16][sub * 32 + quad * 8];
        // ---- wait V (stores from prior group long retired); PV ----
        VMWAIT0();
        f32x4 facc[4];
        #pragma unroll
        for (int a = 0; a < 4; ++a) facc[a] = (f32x4){0.f, 0.f, 0.f, 0.f};
        #pragma unroll
        for (int sub = 0; sub < 4; ++sub) {
            #pragma unroll
            for (int a = 0; a < 4; ++a)
                facc[a] = __builtin_amdgcn_mfma_f32_16x16x32_bf16(pa[sub], vf[sub*4+a], facc[a], 0, 0, 0);
        }
        // ---- epilogue: partial O (C row=node) + per-node (m,l) ----
        unsigned short* po = part_O + (size_t)split * NND * HA;
        #pragma unroll
        for (int a = 0; a < 4; ++a)
            #pragma unroll
            for (int r = 0; r < 4; ++r) {
                const int row = quad * 4 + r;
                if (row < nvalid)
                    po[(size_t)(n0g + row) * HA + h * AA + a * 16 + m16] = f2bf(facc[a][r]);
            }
        if (quad == 0 && m16 < nvalid)
            part_ml[(size_t)split * NND * HH + (size_t)(n0g + m16) * HH + h] =
                make_float2(mx, cs);
        qc0 = qn0; qc1 = qn1;
    }
}

// ---------------------------------------------------------------------------
// Kernel 4: fused combine(8 splits) + gate mul + Wback MFMA + residual + LN.
// (identical to R8)
// ---------------------------------------------------------------------------
__global__ __launch_bounds__(256, 2) void back_ln_fused(
    const unsigned short* __restrict__ part_O, const float2* __restrict__ part_ml,
    const float* __restrict__ gate_ws, const unsigned short* __restrict__ WbackT,
    const float* __restrict__ x, const float* __restrict__ bback,
    const float* __restrict__ gamma, const float* __restrict__ beta,
    float* __restrict__ out)
{
    __shared__ float coef[NSPL][8][8];
    __shared__ unsigned short gf_l[8][520];
    __shared__ float nl[8][260];
    const int t = threadIdx.x, w = t >> 6, lane = t & 63;
    const int m16 = lane & 15, quad = lane >> 4;
    const int r0 = blockIdx.x * 8;
    if (t < 64) {
        const int row = t >> 3, h = t & 7, n = r0 + row;
        float2 ml[NSPL];
        #pragma unroll
        for (int s = 0; s < NSPL; ++s)
            ml[s] = part_ml[(size_t)s * NND * HH + (size_t)n * HH + h];
        float M = -3.0e38f;
        #pragma unroll
        for (int s = 0; s < NSPL; ++s) M = fmaxf(M, ml[s].x);
        float L = 0.f;
        float e[NSPL];
        #pragma unroll
        for (int s = 0; s < NSPL; ++s) { e[s] = __expf(ml[s].x - M); L += ml[s].y * e[s]; }
        const float invL = 1.f / (L + 1e-9f);
        #pragma unroll
        for (int s = 0; s < NSPL; ++s) coef[s][row][h] = e[s] * invL;
    }
    u32x2 pvv[4][NSPL];
    f32x4 gv[4];
    #pragma unroll
    for (int it = 0; it < 4; ++it) {
        const int i = (t + it * 256) * 4;
        const int row = i >> 9, c = i & (HA - 1);
        const int n = r0 + row;
        #pragma unroll
        for (int s = 0; s < NSPL; ++s)
            pvv[it][s] = gld8(&part_O[(size_t)s * NND * HA + (size_t)n * HA + c]);
        gv[it] = gldf4(&gate_ws[(size_t)n * HA + c]);
    }
    __syncthreads();   // coef ready
    VMWAIT0();
    #pragma unroll
    for (int it = 0; it < 4; ++it) {
        const int i = (t + it * 256) * 4;
        const int row = i >> 9, c = i & (HA - 1), h = c >> 6;
        float4 o = make_float4(0.f, 0.f, 0.f, 0.f);
        #pragma unroll
        for (int s = 0; s < NSPL; ++s) {
            const float cf = coef[s][row][h];
            o.x = fmaf(bf2f((unsigned short)(pvv[it][s][0] & 0xffffu)), cf, o.x);
            o.y = fmaf(bf2f((unsigned short)(pvv[it][s][0] >> 16)),     cf, o.y);
            o.z = fmaf(bf2f((unsigned short)(pvv[it][s][1] & 0xffffu)), cf, o.z);
            o.w = fmaf(bf2f((unsigned short)(pvv[it][s][1] >> 16)),     cf, o.w);
        }
        ushort4 ob;
        ob.x = f2bf(gv[it][0] * o.x); ob.y = f2bf(gv[it][1] * o.y);
        ob.z = f2bf(gv[it][2] * o.z); ob.w = f2bf(gv[it][3] * o.w);
        *(ushort4*)&gf_l[row][c] = ob;
    }
    __syncthreads();
    bf16x8 af[16];
    #pragma unroll
    for (int j = 0; j < 16; ++j)
        af[j] = *(const bf16x8*)&gf_l[m16 & 7][quad * 8 + j * 32];
    const unsigned short* bq0 = WbackT + (size_t)(w * 64 +  0 + m16) * HA + quad * 8;
    const unsigned short* bq1 = WbackT + (size_t)(w * 64 + 16 + m16) * HA + quad * 8;
    const unsigned short* bq2 = WbackT + (size_t)(w * 64 + 32 + m16) * HA + quad * 8;
    const unsigned short* bq3 = WbackT + (size_t)(w * 64 + 48 + m16) * HA + quad * 8;
    f32x4 a0 = (f32x4){0.f, 0.f, 0.f, 0.f};
    f32x4 a1 = a0, a2 = a0, a3 = a0;
    #pragma unroll
    for (int jb = 0; jb < 4; ++jb) {
        bf16x8 wb[16];
        #pragma unroll
        for (int j = 0; j < 4; ++j) {
            wb[j*4+0] = gld16(bq0 + (jb*4 + j) * 32);
            wb[j*4+1] = gld16(bq1 + (jb*4 + j) * 32);
            wb[j*4+2] = gld16(bq2 + (jb*4 + j) * 32);
            wb[j*4+3] = gld16(bq3 + (jb*4 + j) * 32);
        }
        VMWAIT0();
        #pragma unroll
        for (int j = 0; j < 4; ++j) {
            a0 = __builtin_amdgcn_mfma_f32_16x16x32_bf16(af[jb*4+j], wb[j*4+0], a0, 0, 0, 0);
            a1 = __builtin_amdgcn_mfma_f32_16x16x32_bf16(af[jb*4+j], wb[j*4+1], a1, 0, 0, 0);
            a2 = __builtin_amdgcn_mfma_f32_16x16x32_bf16(af[jb*4+j], wb[j*4+2], a2, 0, 0, 0);
            a3 = __builtin_amdgcn_mfma_f32_16x16x32_bf16(af[jb*4+j], wb[j*4+3], a3, 0, 0, 0);
        }
    }
    {
        f32x4 dd[4] = {a0, a1, a2, a3};
        #pragma unroll
        for (int u = 0; u < 4; ++u) {
            const int n0 = w * 64 + u * 16;
            const float bb = bback[n0 + m16];
            #pragma unroll
            for (int r = 0; r < 4; ++r) {
                const int rr = quad * 4 + r;
                if (rr < 8) nl[rr][n0 + m16] = dd[u][r] + bb;
            }
        }
    }
    __syncthreads();
    const int row = t >> 5, li = t & 31;
    const float* xr = x + (size_t)(r0 + row) * IFZ;
    float yv[8];
    float s1 = 0.f, s2 = 0.f;
    #pragma unroll
    for (int j = 0; j < 8; ++j) {
        const int c = li + j * 32;
        const float v = fmaf(1.41421356237309515f, xr[c], nl[row][c]);
        yv[j] = v; s1 += v; s2 += v * v;
    }
    #pragma unroll
    for (int off = 16; off >= 1; off >>= 1) {
        s1 += __shfl_xor(s1, off);
        s2 += __shfl_xor(s2, off);
    }
    const float mu  = s1 * (1.f / IFZ);
    const float var = s2 * (1.f / IFZ) - mu * mu;
    const float rv  = rsqrtf(var + 1e-5f);
    float* orow = out + (size_t)(r0 + row) * IFZ;
    #pragma unroll
    for (int j = 0; j < 8; ++j) {
        const int c = li + j * 32;
        orow[c] = (yv[j] - mu) * rv * gamma[c] + beta[c];
    }
}

extern "C" void kernel_launch(void* const* d_in, const int* in_sizes, int n_in,
                              void* d_out, int out_size, void* d_ws, size_t ws_size,
                              hipStream_t stream) {
    const float* x     = (const float*)d_in[0];
    const float* emb   = (const float*)d_in[1];
    const void*  mraw  = d_in[2];
    const void*  braw  = d_in[3];
    const float* Wq    = (const float*)d_in[4];
    const float* Wk    = (const float*)d_in[5];
    const float* Wv    = (const float*)d_in[6];
    const float* Wg    = (const float*)d_in[7];
    const float* bg    = (const float*)d_in[8];
    const float* Wback = (const float*)d_in[9];
    const float* bback = (const float*)d_in[10];
    const float* gamma = (const float*)d_in[11];
    const float* beta  = (const float*)d_in[12];

    char* ws = (char*)d_ws;
    const size_t MB = 1048576;
    size_t off = 0;
    float*          mask_f  = (float*)(ws + off);  off += 16384;
    int*            seg     = (int*)(ws + off);    off += 16384;
    unsigned short* WkT     = (unsigned short*)(ws + off); off += 393216;
    unsigned short* WvT     = (unsigned short*)(ws + off); off += 393216;
    unsigned short* WqT     = (unsigned short*)(ws + off); off += 262144;
    unsigned short* WgT     = (unsigned short*)(ws + off); off += 262144;
    unsigned short* WbackT  = (unsigned short*)(ws + off); off += 262144;
    unsigned short* k_blk   = (unsigned short*)(ws + off); off += 4*MB;
    unsigned short* vT_bf   = (unsigned short*)(ws + off); off += 4*MB;
    unsigned short* q_bf    = (unsigned short*)(ws + off); off += 2*MB;
    float*          gate_ws = (float*)(ws + off); off += 4*MB;
    unsigned short* part_O  = (unsigned short*)(ws + off); off += 16*MB;
    float2*         part_ml = (float2*)(ws + off); off += 1*MB;

    float* out        = (float*)d_out;
    float* out_logits = out + (size_t)NND * IFZ;

    hipLaunchKernelGGL(prep_kernel, dim3(193), dim3(256), 0, stream,
                       Wk, Wv, Wq, Wg, Wback, mraw, braw,
                       WkT, WvT, WqT, WgT, WbackT, mask_f, seg);
    hipLaunchKernelGGL(proj_mfma, dim3(512), dim3(256), 0, stream,
                       emb, x, WkT, WvT, WqT, WgT, bg, k_blk, vT_bf, q_bf, gate_ws);
    hipLaunchKernelGGL(attn_kernel, dim3(ATTN_BLKS + LOGIT_BLKS), dim3(256), 0, stream,
                       k_blk, vT_bf, q_bf, mask_f, seg, part_O, part_ml, out_logits);
    hipLaunchKernelGGL(back_ln_fused, dim3(NND / 8), dim3(256), 0, stream,
                       part_O, part_ml, gate_ws, WbackT, x, bback, gamma, beta, out);
}